// Round 1
// baseline (2425.653 us; speedup 1.0000x reference)
//
#include <hip/hip_runtime.h>

#define EMB 64
#define BNEPS 1e-5f

typedef unsigned short u16;

__device__ __forceinline__ float bf2f(u16 u){
  union { unsigned int i; float f; } v; v.i = ((unsigned int)u) << 16; return v.f;
}
__device__ __forceinline__ u16 f2bf(float x){
  union { float f; unsigned int i; } v; v.f = x;
  unsigned int r = v.i + 0x7FFFu + ((v.i >> 16) & 1u);   // RNE
  return (u16)(r >> 16);
}
__device__ __forceinline__ void atomAddF(float* p, float v){
  __hip_atomic_fetch_add(p, v, __ATOMIC_RELAXED, __HIP_MEMORY_SCOPE_AGENT);
}

// ---------------- zero scratch ----------------
__global__ void kzero(float* __restrict__ p, int n){
  int i = blockIdx.x * blockDim.x + threadIdx.x;
  int st = gridDim.x * blockDim.x;
  for (; i < n; i += st) p[i] = 0.f;
}

// ---------------- per-node edge-endpoint counts ----------------
__global__ void kcount(const int* __restrict__ src, const int* __restrict__ dst,
                       int E, int* __restrict__ cs, int* __restrict__ cd){
  int i = blockIdx.x * blockDim.x + threadIdx.x;
  int st = gridDim.x * blockDim.x;
  for (; i < E; i += st){
    atomicAdd(&cd[dst[i]], 1);
    atomicAdd(&cs[src[i]], 1);
  }
}

// ---------------- (weighted) column-mean + Gram of rows ----------------
// cnt==nullptr -> weight 1 per row.
__global__ __launch_bounds__(256) void kgram(const float* __restrict__ X,
    const int* __restrict__ cnt, int N,
    float* __restrict__ musum, float* __restrict__ S){
  __shared__ float xs[4][EMB];
  __shared__ float cs[4];
  int t = threadIdx.x, r = t >> 6, j = t & 63;
  int a = t >> 2, bb = (t & 3) << 4;
  float g[16];
  #pragma unroll
  for (int i = 0; i < 16; i++) g[i] = 0.f;
  float mup = 0.f;
  for (int n0 = blockIdx.x * 4; n0 < N; n0 += gridDim.x * 4){
    int n = n0 + r; bool ok = n < N;
    xs[r][j] = ok ? X[(size_t)n * EMB + j] : 0.f;
    if (j == 0) cs[r] = ok ? (cnt ? (float)cnt[n] : 1.f) : 0.f;
    __syncthreads();
    #pragma unroll
    for (int rr = 0; rr < 4; rr++){
      float xa = cs[rr] * xs[rr][a];
      const float4* x4 = (const float4*)&xs[rr][bb];
      #pragma unroll
      for (int i4 = 0; i4 < 4; i4++){
        float4 v = x4[i4];
        g[4*i4+0] += xa * v.x; g[4*i4+1] += xa * v.y;
        g[4*i4+2] += xa * v.z; g[4*i4+3] += xa * v.w;
      }
    }
    if (t < EMB) mup += cs[0]*xs[0][t] + cs[1]*xs[1][t] + cs[2]*xs[2][t] + cs[3]*xs[3][t];
    __syncthreads();
  }
  #pragma unroll
  for (int i = 0; i < 16; i++) atomAddF(&S[a * EMB + bb + i], g[i]);
  if (t < EMB) atomAddF(&musum[t], mup);
}

// ---------------- fold BN(stats of h=x@w1+b1) + w2 into (Weff, beff) ----------------
__global__ __launch_bounds__(256) void keffw(const float* __restrict__ musum,
    const float* __restrict__ S, const float* __restrict__ w1, const float* __restrict__ b1,
    const float* __restrict__ w2, const float* __restrict__ b2, float invN,
    float* __restrict__ Weff, float* __restrict__ beff){
  __shared__ float mu[EMB];
  __shared__ float C[EMB][EMB];
  __shared__ float W1p[EMB][EMB + 1];
  __shared__ float c1[EMB];
  __shared__ float istd[EMB];
  __shared__ float red[256];
  int t = threadIdx.x;
  if (t < EMB) mu[t] = musum[t] * invN;
  __syncthreads();
  for (int e = t; e < EMB * EMB; e += 256){
    int k = e >> 6, l = e & 63;
    C[k][l] = S[e] * invN - mu[k] * mu[l];
  }
  __syncthreads();
  {
    int j = t & 63, kg = t >> 6;
    float part = 0.f;
    for (int k = kg * 16; k < kg * 16 + 16; k++){
      float inner = 0.f;
      for (int l = 0; l < EMB; l++) inner += C[k][l] * w1[l * EMB + j];
      part += w1[k * EMB + j] * inner;
    }
    red[t] = part;
  }
  __syncthreads();
  if (t < EMB){
    float var = red[t] + red[t + 64] + red[t + 128] + red[t + 192];
    float is = 1.0f / sqrtf(var + BNEPS);
    istd[t] = is;
    float muh = 0.f;
    for (int k = 0; k < EMB; k++) muh += mu[k] * w1[k * EMB + t];
    muh += b1[t];
    c1[t] = (b1[t] - muh) * is;
  }
  __syncthreads();
  for (int e = t; e < EMB * EMB; e += 256){
    int k = e >> 6, j = e & 63;
    W1p[k][j] = w1[e] * istd[j];
  }
  __syncthreads();
  {
    int k = t >> 2, j2b = (t & 3) << 4;
    float acc[16];
    #pragma unroll
    for (int i = 0; i < 16; i++) acc[i] = 0.f;
    for (int j = 0; j < EMB; j++){
      float wp = W1p[k][j];
      const float* w2r = &w2[j * EMB + j2b];
      #pragma unroll
      for (int i = 0; i < 16; i++) acc[i] += wp * w2r[i];
    }
    #pragma unroll
    for (int i = 0; i < 16; i++) Weff[k * EMB + j2b + i] = acc[i];
  }
  if (t < EMB){
    float acc = b2[t];
    for (int j = 0; j < EMB; j++) acc += c1[j] * w2[j * EMB + t];
    beff[t] = acc;
  }
}

// ---------------- per-node: P = relu(x@Weff+beff) @ Wslice ----------------
__global__ __launch_bounds__(256) void knodeMP(const float* __restrict__ X,
    const float* __restrict__ Weff, const float* __restrict__ beff,
    const float* __restrict__ Wslice, int N, float* __restrict__ P){
  __shared__ float xs[4][EMB];
  __shared__ float ms[4][EMB];
  __shared__ float be[EMB];
  int t = threadIdx.x, r = t >> 6, j = t & 63;
  float wA[EMB], wB[EMB];
  #pragma unroll
  for (int k = 0; k < EMB; k++){ wA[k] = Weff[k * EMB + j]; wB[k] = Wslice[k * EMB + j]; }
  if (t < EMB) be[t] = beff[t];
  __syncthreads();
  for (int n0 = blockIdx.x * 4; n0 < N; n0 += gridDim.x * 4){
    int n = n0 + r; bool ok = n < N;
    xs[r][j] = ok ? X[(size_t)n * EMB + j] : 0.f;
    __syncthreads();
    float a0 = be[j], a1 = 0.f, a2 = 0.f, a3 = 0.f;
    const float4* x4 = (const float4*)xs[r];
    #pragma unroll
    for (int kb = 0; kb < 16; kb++){
      float4 v = x4[kb];
      a0 += v.x * wA[4*kb]; a1 += v.y * wA[4*kb+1];
      a2 += v.z * wA[4*kb+2]; a3 += v.w * wA[4*kb+3];
    }
    ms[r][j] = fmaxf((a0 + a1) + (a2 + a3), 0.f);
    __syncthreads();
    float p0 = 0.f, p1 = 0.f, p2 = 0.f, p3 = 0.f;
    const float4* m4 = (const float4*)ms[r];
    #pragma unroll
    for (int kb = 0; kb < 16; kb++){
      float4 v = m4[kb];
      p0 += v.x * wB[4*kb]; p1 += v.y * wB[4*kb+1];
      p2 += v.z * wB[4*kb+2]; p3 += v.w * wB[4*kb+3];
    }
    if (ok) P[(size_t)n * EMB + j] = (p0 + p1) + (p2 + p3);
    __syncthreads();
  }
}

// ---------------- pass 1: per-edge h = P_i[dst]+P_j[src]+relu(xe@We+be)@B+bf1 ----------------
__global__ __launch_bounds__(256) void kpass1(const float* __restrict__ XE,
    const int* __restrict__ srcv, const int* __restrict__ dstv,
    const float* __restrict__ Weff_e, const float* __restrict__ beff_e,
    const float* __restrict__ Bw, const float* __restrict__ bf1,
    const float* __restrict__ P_i, const float* __restrict__ P_j, int E,
    u16* __restrict__ hbf, float* __restrict__ hsum, float* __restrict__ hsq){
  __shared__ float xs[4][EMB];
  __shared__ float ms[4][EMB];
  __shared__ float bsh[2][EMB];
  __shared__ int idxs[4][2];
  __shared__ float red[256];
  int t = threadIdx.x, r = t >> 6, j = t & 63;
  float wA[EMB], wB[EMB];
  #pragma unroll
  for (int k = 0; k < EMB; k++){ wA[k] = Weff_e[k * EMB + j]; wB[k] = Bw[k * EMB + j]; }
  if (t < EMB){ bsh[0][t] = beff_e[t]; bsh[1][t] = bf1[t]; }
  __syncthreads();
  float psum = 0.f, psq = 0.f;
  for (int e0 = blockIdx.x * 4; e0 < E; e0 += gridDim.x * 4){
    int e = e0 + r; bool ok = e < E;
    xs[r][j] = ok ? XE[(size_t)e * EMB + j] : 0.f;
    if (t < 8){
      int rr = t >> 1, ee = e0 + rr;
      idxs[rr][t & 1] = (ee < E) ? ((t & 1) ? dstv[ee] : srcv[ee]) : 0;
    }
    __syncthreads();
    float a0 = bsh[0][j], a1 = 0.f, a2 = 0.f, a3 = 0.f;
    const float4* x4 = (const float4*)xs[r];
    #pragma unroll
    for (int kb = 0; kb < 16; kb++){
      float4 v = x4[kb];
      a0 += v.x * wA[4*kb]; a1 += v.y * wA[4*kb+1];
      a2 += v.z * wA[4*kb+2]; a3 += v.w * wA[4*kb+3];
    }
    ms[r][j] = fmaxf((a0 + a1) + (a2 + a3), 0.f);
    __syncthreads();
    float h0 = bsh[1][j], h1 = 0.f, h2 = 0.f, h3 = 0.f;
    const float4* m4 = (const float4*)ms[r];
    #pragma unroll
    for (int kb = 0; kb < 16; kb++){
      float4 v = m4[kb];
      h0 += v.x * wB[4*kb]; h1 += v.y * wB[4*kb+1];
      h2 += v.z * wB[4*kb+2]; h3 += v.w * wB[4*kb+3];
    }
    if (ok){
      int s = idxs[r][0], d = idxs[r][1];
      float h = (h0 + h1) + (h2 + h3);
      h += P_i[(size_t)d * EMB + j] + P_j[(size_t)s * EMB + j];
      hbf[(size_t)e * EMB + j] = f2bf(h);
      psum += h; psq += h * h;
    }
    __syncthreads();
  }
  red[t] = psum; __syncthreads();
  if (t < EMB) atomAddF(&hsum[t], red[t] + red[t + 64] + red[t + 128] + red[t + 192]);
  __syncthreads();
  red[t] = psq; __syncthreads();
  if (t < EMB) atomAddF(&hsq[t], red[t] + red[t + 64] + red[t + 128] + red[t + 192]);
}

// ---------------- fold BN stats (sum/sumsq of h) + w2 into (W2p, b2p) ----------------
__global__ __launch_bounds__(256) void kbnfold(const float* __restrict__ hsum,
    const float* __restrict__ hsq, float invN, const float* __restrict__ w2,
    const float* __restrict__ b2, float* __restrict__ W2p, float* __restrict__ b2p){
  __shared__ float mu[EMB], istd[EMB];
  int t = threadIdx.x;
  if (t < EMB){
    float m = hsum[t] * invN;
    float var = hsq[t] * invN - m * m;
    mu[t] = m; istd[t] = 1.0f / sqrtf(var + BNEPS);
  }
  __syncthreads();
  for (int e = t; e < EMB * EMB; e += 256){
    int k = e >> 6;
    W2p[e] = istd[k] * w2[e];
  }
  if (t < EMB){
    float acc = b2[t];
    for (int k = 0; k < EMB; k++) acc -= mu[k] * istd[k] * w2[k * EMB + t];
    b2p[t] = acc;
  }
}

// ---------------- pass 2: msg = relu(h@W2p+b2p); agg[dst] += msg ----------------
__global__ __launch_bounds__(256) void kpass2(const u16* __restrict__ hbf,
    const int* __restrict__ dstv, const float* __restrict__ W2p,
    const float* __restrict__ b2p, int E, float* __restrict__ agg){
  __shared__ float hs[4][EMB];
  __shared__ float bsh[EMB];
  __shared__ int ds[4];
  int t = threadIdx.x, r = t >> 6, j = t & 63;
  float wc[EMB];
  #pragma unroll
  for (int k = 0; k < EMB; k++) wc[k] = W2p[k * EMB + j];
  if (t < EMB) bsh[t] = b2p[t];
  __syncthreads();
  for (int e0 = blockIdx.x * 4; e0 < E; e0 += gridDim.x * 4){
    int e = e0 + r; bool ok = e < E;
    hs[r][j] = ok ? bf2f(hbf[(size_t)e * EMB + j]) : 0.f;
    if (t < 4) ds[t] = (e0 + t < E) ? dstv[e0 + t] : 0;
    __syncthreads();
    float a0 = bsh[j], a1 = 0.f, a2 = 0.f, a3 = 0.f;
    const float4* h4 = (const float4*)hs[r];
    #pragma unroll
    for (int kb = 0; kb < 16; kb++){
      float4 v = h4[kb];
      a0 += v.x * wc[4*kb]; a1 += v.y * wc[4*kb+1];
      a2 += v.z * wc[4*kb+2]; a3 += v.w * wc[4*kb+3];
    }
    if (ok) atomAddF(&agg[(size_t)ds[r] * EMB + j], fmaxf((a0 + a1) + (a2 + a3), 0.f));
    __syncthreads();
  }
}

// ---------------- output stage 1: h_o = [agg/cnt, right] @ ow1 + ob1 (+ stats) ----------------
__global__ __launch_bounds__(256) void kout1(const float* __restrict__ agg,
    const int* __restrict__ cnt, const float* __restrict__ right,
    const float* __restrict__ ow1, const float* __restrict__ ob1, int N,
    float* __restrict__ h_o, float* __restrict__ osum, float* __restrict__ osq){
  __shared__ float xs[4][2 * EMB];
  __shared__ float bsh[EMB];
  __shared__ float red[256];
  int t = threadIdx.x, r = t >> 6, j = t & 63;
  float wc[2 * EMB];
  #pragma unroll
  for (int k = 0; k < 2 * EMB; k++) wc[k] = ow1[k * EMB + j];
  if (t < EMB) bsh[t] = ob1[t];
  __syncthreads();
  float psum = 0.f, psq = 0.f;
  for (int n0 = blockIdx.x * 4; n0 < N; n0 += gridDim.x * 4){
    int n = n0 + r; bool ok = n < N;
    if (ok){
      float c = fmaxf((float)cnt[n], 1.f);
      xs[r][j] = agg[(size_t)n * EMB + j] / c;
      xs[r][EMB + j] = right[(size_t)n * EMB + j];
    } else { xs[r][j] = 0.f; xs[r][EMB + j] = 0.f; }
    __syncthreads();
    float a0 = bsh[j], a1 = 0.f, a2 = 0.f, a3 = 0.f;
    const float4* x4 = (const float4*)xs[r];
    #pragma unroll
    for (int kb = 0; kb < 32; kb++){
      float4 v = x4[kb];
      a0 += v.x * wc[4*kb]; a1 += v.y * wc[4*kb+1];
      a2 += v.z * wc[4*kb+2]; a3 += v.w * wc[4*kb+3];
    }
    if (ok){
      float h = (a0 + a1) + (a2 + a3);
      h_o[(size_t)n * EMB + j] = h;
      psum += h; psq += h * h;
    }
    __syncthreads();
  }
  red[t] = psum; __syncthreads();
  if (t < EMB) atomAddF(&osum[t], red[t] + red[t + 64] + red[t + 128] + red[t + 192]);
  __syncthreads();
  red[t] = psq; __syncthreads();
  if (t < EMB) atomAddF(&osq[t], red[t] + red[t + 64] + red[t + 128] + red[t + 192]);
}

// ---------------- output stage 2: out = relu(h_o @ W2o + b2o) ----------------
__global__ __launch_bounds__(256) void kout2(const float* __restrict__ h_o,
    const float* __restrict__ W2o, const float* __restrict__ b2o, int N,
    float* __restrict__ out){
  __shared__ float hs[4][EMB];
  __shared__ float bsh[EMB];
  int t = threadIdx.x, r = t >> 6, j = t & 63;
  float wc[EMB];
  #pragma unroll
  for (int k = 0; k < EMB; k++) wc[k] = W2o[k * EMB + j];
  if (t < EMB) bsh[t] = b2o[t];
  __syncthreads();
  for (int n0 = blockIdx.x * 4; n0 < N; n0 += gridDim.x * 4){
    int n = n0 + r; bool ok = n < N;
    hs[r][j] = ok ? h_o[(size_t)n * EMB + j] : 0.f;
    __syncthreads();
    float a0 = bsh[j], a1 = 0.f, a2 = 0.f, a3 = 0.f;
    const float4* h4 = (const float4*)hs[r];
    #pragma unroll
    for (int kb = 0; kb < 16; kb++){
      float4 v = h4[kb];
      a0 += v.x * wc[4*kb]; a1 += v.y * wc[4*kb+1];
      a2 += v.z * wc[4*kb+2]; a3 += v.w * wc[4*kb+3];
    }
    if (ok) out[(size_t)n * EMB + j] = fmaxf((a0 + a1) + (a2 + a3), 0.f);
    __syncthreads();
  }
}

extern "C" void kernel_launch(void* const* d_in, const int* in_sizes, int n_in,
                              void* d_out, int out_size, void* d_ws, size_t ws_size,
                              hipStream_t stream){
  const float* left   = (const float*)d_in[0];
  const float* right  = (const float*)d_in[1];
  const float* edgef  = (const float*)d_in[2];
  const int*   eidx   = (const int*)d_in[3];
  const float* fmr_w1 = (const float*)d_in[4];  const float* fmr_b1 = (const float*)d_in[5];
  const float* fmr_w2 = (const float*)d_in[6];  const float* fmr_b2 = (const float*)d_in[7];
  const float* fme_w1 = (const float*)d_in[8];  const float* fme_b1 = (const float*)d_in[9];
  const float* fme_w2 = (const float*)d_in[10]; const float* fme_b2 = (const float*)d_in[11];
  const float* fmf_w1 = (const float*)d_in[12]; const float* fmf_b1 = (const float*)d_in[13];
  const float* fmf_w2 = (const float*)d_in[14]; const float* fmf_b2 = (const float*)d_in[15];
  const float* ow1    = (const float*)d_in[16]; const float* ob1    = (const float*)d_in[17];
  const float* ow2    = (const float*)d_in[18]; const float* ob2    = (const float*)d_in[19];

  int NL = in_sizes[0] / EMB;
  int NR = in_sizes[1] / EMB;
  int E  = in_sizes[2] / EMB;
  const int* srcv = eidx;
  const int* dstv = eidx + E;

  char* base = (char*)d_ws;
  size_t o = 0;
  u16* hbf = (u16*)(base + o);      o += (size_t)E * EMB * sizeof(u16);
  float* P_i  = (float*)(base + o); o += (size_t)NR * EMB * 4;
  float* P_j  = (float*)(base + o); o += (size_t)NL * EMB * 4;
  float* h_o  = (float*)(base + o); o += (size_t)NR * EMB * 4;
  float* Weff_i = (float*)(base + o); o += EMB * EMB * 4;
  float* beff_i = (float*)(base + o); o += EMB * 4;
  float* Weff_j = (float*)(base + o); o += EMB * EMB * 4;
  float* beff_j = (float*)(base + o); o += EMB * 4;
  float* Weff_e = (float*)(base + o); o += EMB * EMB * 4;
  float* beff_e = (float*)(base + o); o += EMB * 4;
  float* W2p  = (float*)(base + o); o += EMB * EMB * 4;
  float* b2p  = (float*)(base + o); o += EMB * 4;
  float* W2o  = (float*)(base + o); o += EMB * EMB * 4;
  float* b2o  = (float*)(base + o); o += EMB * 4;
  // ---- zeroed region starts here ----
  char* zstart = base + o;
  float* agg     = (float*)(base + o); o += (size_t)NR * EMB * 4;
  int* cnt_dst   = (int*)(base + o);   o += (size_t)NR * 4;
  int* cnt_src   = (int*)(base + o);   o += (size_t)NL * 4;
  float* musum_i = (float*)(base + o); o += EMB * 4;
  float* S_i     = (float*)(base + o); o += EMB * EMB * 4;
  float* musum_j = (float*)(base + o); o += EMB * 4;
  float* S_j     = (float*)(base + o); o += EMB * EMB * 4;
  float* musum_e = (float*)(base + o); o += EMB * 4;
  float* S_e     = (float*)(base + o); o += EMB * EMB * 4;
  float* hsum    = (float*)(base + o); o += EMB * 4;
  float* hsq     = (float*)(base + o); o += EMB * 4;
  float* osum    = (float*)(base + o); o += EMB * 4;
  float* osq     = (float*)(base + o); o += EMB * 4;
  int zn = (int)(((base + o) - zstart) / 4);

  float invE = 1.0f / (float)E;
  float invNR = 1.0f / (float)NR;

  kzero<<<512, 256, 0, stream>>>((float*)zstart, zn);
  kcount<<<512, 256, 0, stream>>>(srcv, dstv, E, cnt_src, cnt_dst);
  kgram<<<256, 256, 0, stream>>>(right, cnt_dst, NR, musum_i, S_i);
  kgram<<<256, 256, 0, stream>>>(left,  cnt_src, NL, musum_j, S_j);
  kgram<<<512, 256, 0, stream>>>(edgef, (const int*)nullptr, E, musum_e, S_e);
  keffw<<<1, 256, 0, stream>>>(musum_i, S_i, fmr_w1, fmr_b1, fmr_w2, fmr_b2, invE, Weff_i, beff_i);
  keffw<<<1, 256, 0, stream>>>(musum_j, S_j, fmr_w1, fmr_b1, fmr_w2, fmr_b2, invE, Weff_j, beff_j);
  keffw<<<1, 256, 0, stream>>>(musum_e, S_e, fme_w1, fme_b1, fme_w2, fme_b2, invE, Weff_e, beff_e);
  knodeMP<<<1024, 256, 0, stream>>>(right, Weff_i, beff_i, fmf_w1,                 NR, P_i);
  knodeMP<<<1024, 256, 0, stream>>>(left,  Weff_j, beff_j, fmf_w1 + 2 * EMB * EMB, NL, P_j);
  kpass1<<<2048, 256, 0, stream>>>(edgef, srcv, dstv, Weff_e, beff_e,
                                   fmf_w1 + EMB * EMB, fmf_b1, P_i, P_j, E, hbf, hsum, hsq);
  kbnfold<<<1, 256, 0, stream>>>(hsum, hsq, invE, fmf_w2, fmf_b2, W2p, b2p);
  kpass2<<<2048, 256, 0, stream>>>(hbf, dstv, W2p, b2p, E, agg);
  kout1<<<1024, 256, 0, stream>>>(agg, cnt_dst, right, ow1, ob1, NR, h_o, osum, osq);
  kbnfold<<<1, 256, 0, stream>>>(osum, osq, invNR, ow2, ob2, W2o, b2o);
  kout2<<<1024, 256, 0, stream>>>(h_o, W2o, b2o, NR, (float*)d_out);
}

// Round 2
// 1824.116 us; speedup vs baseline: 1.3298x; 1.3298x over previous
//
#include <hip/hip_runtime.h>

#define EMB 64
#define BNEPS 1e-5f

typedef unsigned short u16;
typedef float f32x4 __attribute__((ext_vector_type(4)));
typedef short bf16x8 __attribute__((ext_vector_type(8)));

__device__ __forceinline__ float bf2f(u16 u){
  union { unsigned int i; float f; } v; v.i = ((unsigned int)u) << 16; return v.f;
}
__device__ __forceinline__ u16 f2bf(float x){
  union { float f; unsigned int i; } v; v.f = x;
  unsigned int r = v.i + 0x7FFFu + ((v.i >> 16) & 1u);   // RNE
  return (u16)(r >> 16);
}
__device__ __forceinline__ void atomAddF(float* p, float v){
  __hip_atomic_fetch_add(p, v, __ATOMIC_RELAXED, __HIP_MEMORY_SCOPE_AGENT);
}

// ---------------- zero scratch ----------------
__global__ void kzero(float* __restrict__ p, int n){
  int i = blockIdx.x * blockDim.x + threadIdx.x;
  int st = gridDim.x * blockDim.x;
  for (; i < n; i += st) p[i] = 0.f;
}

// ---------------- per-node edge-endpoint counts ----------------
__global__ void kcount(const int* __restrict__ src, const int* __restrict__ dst,
                       int E, int* __restrict__ cs, int* __restrict__ cd){
  int i = blockIdx.x * blockDim.x + threadIdx.x;
  int st = gridDim.x * blockDim.x;
  for (; i < E; i += st){
    atomicAdd(&cd[dst[i]], 1);
    atomicAdd(&cs[src[i]], 1);
  }
}

// ---------------- (weighted) column-mean + Gram of rows (node-scale, fp32) ----------------
__global__ __launch_bounds__(256) void kgram(const float* __restrict__ X,
    const int* __restrict__ cnt, int N,
    float* __restrict__ musum, float* __restrict__ S){
  __shared__ float xs[4][EMB];
  __shared__ float cs[4];
  int t = threadIdx.x, r = t >> 6, j = t & 63;
  int a = t >> 2, bb = (t & 3) << 4;
  float g[16];
  #pragma unroll
  for (int i = 0; i < 16; i++) g[i] = 0.f;
  float mup = 0.f;
  for (int n0 = blockIdx.x * 4; n0 < N; n0 += gridDim.x * 4){
    int n = n0 + r; bool ok = n < N;
    xs[r][j] = ok ? X[(size_t)n * EMB + j] : 0.f;
    if (j == 0) cs[r] = ok ? (cnt ? (float)cnt[n] : 1.f) : 0.f;
    __syncthreads();
    #pragma unroll
    for (int rr = 0; rr < 4; rr++){
      float xa = cs[rr] * xs[rr][a];
      const float4* x4 = (const float4*)&xs[rr][bb];
      #pragma unroll
      for (int i4 = 0; i4 < 4; i4++){
        float4 v = x4[i4];
        g[4*i4+0] += xa * v.x; g[4*i4+1] += xa * v.y;
        g[4*i4+2] += xa * v.z; g[4*i4+3] += xa * v.w;
      }
    }
    if (t < EMB) mup += cs[0]*xs[0][t] + cs[1]*xs[1][t] + cs[2]*xs[2][t] + cs[3]*xs[3][t];
    __syncthreads();
  }
  #pragma unroll
  for (int i = 0; i < 16; i++) atomAddF(&S[a * EMB + bb + i], g[i]);
  if (t < EMB) atomAddF(&musum[t], mup);
}

// ---------------- MFMA Gram + column means over edge features ----------------
// Stages 64-edge tile transposed (XT[k][e], bf16, pad 72) in LDS.
// Assumes N % 64 == 0 (true for this workload: 1M edges).
__global__ __launch_bounds__(256) void kprepm(const float* __restrict__ XE, int N,
    float* __restrict__ musum, float* __restrict__ S){
  __shared__ __align__(16) u16 XT[64 * 72];
  int t = threadIdx.x, l = t & 63, wv = t >> 6, g = l >> 4, e16 = l & 15;
  f32x4 C[4];
  #pragma unroll
  for (int mb = 0; mb < 4; mb++) C[mb] = (f32x4){0.f,0.f,0.f,0.f};
  float ms[4] = {0.f, 0.f, 0.f, 0.f};
  int ntiles = N >> 6;
  for (int T = blockIdx.x; T < ntiles; T += gridDim.x){
    __syncthreads();
    #pragma unroll
    for (int i = 0; i < 4; i++){
      int c = t + i * 256;
      int row = c >> 4, k0 = (c & 15) << 2;
      f32x4 v = *(const f32x4*)(XE + ((size_t)T * 64 + row) * EMB + k0);
      #pragma unroll
      for (int q = 0; q < 4; q++){
        ms[q] += v[q];
        XT[(k0 + q) * 72 + row] = f2bf(v[q]);
      }
    }
    __syncthreads();
    #pragma unroll
    for (int kf = 0; kf < 2; kf++){
      bf16x8 fr[4];
      #pragma unroll
      for (int mb = 0; mb < 4; mb++)
        fr[mb] = *(const bf16x8*)&XT[(mb*16 + e16) * 72 + kf*32 + g*8];
      bf16x8 bfr = *(const bf16x8*)&XT[(wv*16 + e16) * 72 + kf*32 + g*8];
      #pragma unroll
      for (int mb = 0; mb < 4; mb++)
        C[mb] = __builtin_amdgcn_mfma_f32_16x16x32_bf16(fr[mb], bfr, C[mb], 0, 0, 0);
    }
  }
  // S partials: lane holds S[mb*16+g*4+reg][wv*16+e16]
  #pragma unroll
  for (int mb = 0; mb < 4; mb++)
    #pragma unroll
    for (int r = 0; r < 4; r++)
      atomAddF(&S[(mb*16 + g*4 + r) * EMB + wv*16 + e16], C[mb][r]);
  // musum: block-level combine then atomic
  __syncthreads();
  float* red = (float*)XT;
  #pragma unroll
  for (int q = 0; q < 4; q++){
    float x = ms[q];
    x += __shfl_xor(x, 16); x += __shfl_xor(x, 32);
    if (l < 16) red[(wv*16 + l)*4 + q] = x;
  }
  __syncthreads();
  if (t < 64){
    int k = t >> 2, q = t & 3;
    float s = red[(k)*4+q] + red[(16+k)*4+q] + red[(32+k)*4+q] + red[(48+k)*4+q];
    atomAddF(&musum[k*4 + q], s);
  }
}

// ---------------- fold BN(stats of h=x@w1+b1) + w2 into (Weff, beff) ----------------
__global__ __launch_bounds__(256) void keffw(const float* __restrict__ musum,
    const float* __restrict__ S, const float* __restrict__ w1, const float* __restrict__ b1,
    const float* __restrict__ w2, const float* __restrict__ b2, float invN,
    float* __restrict__ Weff, float* __restrict__ beff){
  __shared__ float mu[EMB];
  __shared__ float C[EMB][EMB];
  __shared__ float W1p[EMB][EMB + 1];
  __shared__ float c1[EMB];
  __shared__ float istd[EMB];
  __shared__ float red[256];
  int t = threadIdx.x;
  if (t < EMB) mu[t] = musum[t] * invN;
  __syncthreads();
  for (int e = t; e < EMB * EMB; e += 256){
    int k = e >> 6, l = e & 63;
    C[k][l] = S[e] * invN - mu[k] * mu[l];
  }
  __syncthreads();
  {
    int j = t & 63, kg = t >> 6;
    float part = 0.f;
    for (int k = kg * 16; k < kg * 16 + 16; k++){
      float inner = 0.f;
      for (int l = 0; l < EMB; l++) inner += C[k][l] * w1[l * EMB + j];
      part += w1[k * EMB + j] * inner;
    }
    red[t] = part;
  }
  __syncthreads();
  if (t < EMB){
    float var = red[t] + red[t + 64] + red[t + 128] + red[t + 192];
    float is = 1.0f / sqrtf(var + BNEPS);
    istd[t] = is;
    float muh = 0.f;
    for (int k = 0; k < EMB; k++) muh += mu[k] * w1[k * EMB + t];
    muh += b1[t];
    c1[t] = (b1[t] - muh) * is;
  }
  __syncthreads();
  for (int e = t; e < EMB * EMB; e += 256){
    int k = e >> 6, j = e & 63;
    W1p[k][j] = w1[e] * istd[j];
  }
  __syncthreads();
  {
    int k = t >> 2, j2b = (t & 3) << 4;
    float acc[16];
    #pragma unroll
    for (int i = 0; i < 16; i++) acc[i] = 0.f;
    for (int j = 0; j < EMB; j++){
      float wp = W1p[k][j];
      const float* w2r = &w2[j * EMB + j2b];
      #pragma unroll
      for (int i = 0; i < 16; i++) acc[i] += wp * w2r[i];
    }
    #pragma unroll
    for (int i = 0; i < 16; i++) Weff[k * EMB + j2b + i] = acc[i];
  }
  if (t < EMB){
    float acc = b2[t];
    for (int j = 0; j < EMB; j++) acc += c1[j] * w2[j * EMB + t];
    beff[t] = acc;
  }
}

// ---------------- per-node: P = relu(x@Weff+beff) @ Wslice ----------------
__global__ __launch_bounds__(256) void knodeMP(const float* __restrict__ X,
    const float* __restrict__ Weff, const float* __restrict__ beff,
    const float* __restrict__ Wslice, int N, float* __restrict__ P){
  __shared__ float xs[4][EMB];
  __shared__ float ms[4][EMB];
  __shared__ float be[EMB];
  int t = threadIdx.x, r = t >> 6, j = t & 63;
  float wA[EMB], wB[EMB];
  #pragma unroll
  for (int k = 0; k < EMB; k++){ wA[k] = Weff[k * EMB + j]; wB[k] = Wslice[k * EMB + j]; }
  if (t < EMB) be[t] = beff[t];
  __syncthreads();
  for (int n0 = blockIdx.x * 4; n0 < N; n0 += gridDim.x * 4){
    int n = n0 + r; bool ok = n < N;
    xs[r][j] = ok ? X[(size_t)n * EMB + j] : 0.f;
    __syncthreads();
    float a0 = be[j], a1 = 0.f, a2 = 0.f, a3 = 0.f;
    const float4* x4 = (const float4*)xs[r];
    #pragma unroll
    for (int kb = 0; kb < 16; kb++){
      float4 v = x4[kb];
      a0 += v.x * wA[4*kb]; a1 += v.y * wA[4*kb+1];
      a2 += v.z * wA[4*kb+2]; a3 += v.w * wA[4*kb+3];
    }
    ms[r][j] = fmaxf((a0 + a1) + (a2 + a3), 0.f);
    __syncthreads();
    float p0 = 0.f, p1 = 0.f, p2 = 0.f, p3 = 0.f;
    const float4* m4 = (const float4*)ms[r];
    #pragma unroll
    for (int kb = 0; kb < 16; kb++){
      float4 v = m4[kb];
      p0 += v.x * wB[4*kb]; p1 += v.y * wB[4*kb+1];
      p2 += v.z * wB[4*kb+2]; p3 += v.w * wB[4*kb+3];
    }
    if (ok) P[(size_t)n * EMB + j] = (p0 + p1) + (p2 + p3);
    __syncthreads();
  }
}

// ---------------- MFMA pass 1 ----------------
// Per wave: 16 edges. Layer1 transposed (A=Weff^T frags, B=X frags from global),
// pi-permutation makes layer1 C-frags directly the layer2 A-frags.
// h stored fragment-major bf16: hbf[((T*2+kf)*64 + lane)*8 + i].
// Assumes E % 16 == 0 (true: 1M edges).
__global__ __launch_bounds__(256) void kpass1m(const float* __restrict__ XE,
    const int* __restrict__ srcv, const int* __restrict__ dstv,
    const float* __restrict__ Weff_e, const float* __restrict__ beff_e,
    const float* __restrict__ Bw, const float* __restrict__ bf1,
    const float* __restrict__ P_i, const float* __restrict__ P_j, int ntiles,
    u16* __restrict__ hbf, float* __restrict__ hsum, float* __restrict__ hsq){
  int t = threadIdx.x, l = t & 63, wv = t >> 6, g = l >> 4, e16 = l & 15;
  // preload weight fragments (bf16)
  bf16x8 a1w[4][2], a2w[4][2];
  #pragma unroll
  for (int mb = 0; mb < 4; mb++)
    #pragma unroll
    for (int kf = 0; kf < 2; kf++)
      #pragma unroll
      for (int i = 0; i < 8; i++){
        a1w[mb][kf][i] = (short)f2bf(Weff_e[(kf*32 + g*8 + i) * EMB + mb*16 + e16]);
        int c = (kf + 2*(i>>2))*16 + g*4 + (i&3);              // pi^-1
        a2w[mb][kf][i] = (short)f2bf(Bw[c * EMB + mb*16 + e16]);
      }
  f32x4 b1v[4], b2v[4];
  #pragma unroll
  for (int mb = 0; mb < 4; mb++)
    #pragma unroll
    for (int r = 0; r < 4; r++){
      b1v[mb][r] = beff_e[mb*16 + g*4 + r];
      b2v[mb][r] = bf1[mb*16 + g*4 + r];
    }
  f32x4 ps[4], pq[4];
  #pragma unroll
  for (int mb = 0; mb < 4; mb++){ ps[mb] = (f32x4){0,0,0,0}; pq[mb] = (f32x4){0,0,0,0}; }

  int gw = blockIdx.x * 4 + wv, nw = gridDim.x * 4;
  for (int T = gw; T < ntiles; T += nw){
    int erow = T * 16 + e16;
    const float* xr = XE + (size_t)erow * EMB;
    f32x4 x0 = *(const f32x4*)(xr + g*8);
    f32x4 x1 = *(const f32x4*)(xr + g*8 + 4);
    f32x4 x2 = *(const f32x4*)(xr + 32 + g*8);
    f32x4 x3 = *(const f32x4*)(xr + 36 + g*8);
    int d = dstv[erow], s = srcv[erow];
    const float* pid = P_i + (size_t)d * EMB;
    const float* pjs = P_j + (size_t)s * EMB;
    // init layer2 accum with bias + P gathers
    f32x4 C2[4];
    #pragma unroll
    for (int mb = 0; mb < 4; mb++)
      #pragma unroll
      for (int r = 0; r < 4; r++){
        int j = mb*16 + g*4 + r;
        C2[mb][r] = b2v[mb][r] + pid[j] + pjs[j];
      }
    // X frags
    bf16x8 xf0, xf1;
    #pragma unroll
    for (int q = 0; q < 4; q++){
      xf0[q]   = (short)f2bf(x0[q]); xf0[4+q] = (short)f2bf(x1[q]);
      xf1[q]   = (short)f2bf(x2[q]); xf1[4+q] = (short)f2bf(x3[q]);
    }
    // layer 1 (transposed): C1[mb] = T1[c][e], c = mb*16+g*4+reg, e = e16
    f32x4 C1[4];
    #pragma unroll
    for (int mb = 0; mb < 4; mb++) C1[mb] = b1v[mb];
    #pragma unroll
    for (int mb = 0; mb < 4; mb++){
      C1[mb] = __builtin_amdgcn_mfma_f32_16x16x32_bf16(a1w[mb][0], xf0, C1[mb], 0, 0, 0);
      C1[mb] = __builtin_amdgcn_mfma_f32_16x16x32_bf16(a1w[mb][1], xf1, C1[mb], 0, 0, 0);
    }
    // relu + pack into layer2 A-frags via pi
    bf16x8 mfr0, mfr1;
    #pragma unroll
    for (int q = 0; q < 4; q++){
      mfr0[q]   = (short)f2bf(fmaxf(C1[0][q], 0.f));
      mfr0[4+q] = (short)f2bf(fmaxf(C1[2][q], 0.f));
      mfr1[q]   = (short)f2bf(fmaxf(C1[1][q], 0.f));
      mfr1[4+q] = (short)f2bf(fmaxf(C1[3][q], 0.f));
    }
    // layer 2 (transposed)
    #pragma unroll
    for (int mb = 0; mb < 4; mb++){
      C2[mb] = __builtin_amdgcn_mfma_f32_16x16x32_bf16(a2w[mb][0], mfr0, C2[mb], 0, 0, 0);
      C2[mb] = __builtin_amdgcn_mfma_f32_16x16x32_bf16(a2w[mb][1], mfr1, C2[mb], 0, 0, 0);
    }
    // stats
    #pragma unroll
    for (int mb = 0; mb < 4; mb++){ ps[mb] += C2[mb]; pq[mb] += C2[mb] * C2[mb]; }
    // store h as pi-permuted frags (coalesced 16B/lane)
    bf16x8 h0, h1;
    #pragma unroll
    for (int q = 0; q < 4; q++){
      h0[q]   = (short)f2bf(C2[0][q]); h0[4+q] = (short)f2bf(C2[2][q]);
      h1[q]   = (short)f2bf(C2[1][q]); h1[4+q] = (short)f2bf(C2[3][q]);
    }
    *(bf16x8*)(hbf + ((size_t)(T*2 + 0) * 64 + l) * 8) = h0;
    *(bf16x8*)(hbf + ((size_t)(T*2 + 1) * 64 + l) * 8) = h1;
  }
  // reduce stats across the 16 edges (lanes within 16-group)
  #pragma unroll
  for (int mb = 0; mb < 4; mb++)
    #pragma unroll
    for (int r = 0; r < 4; r++){
      float v = ps[mb][r], u = pq[mb][r];
      #pragma unroll
      for (int m = 1; m < 16; m <<= 1){ v += __shfl_xor(v, m); u += __shfl_xor(u, m); }
      if (e16 == 0){
        int j = mb*16 + g*4 + r;
        atomAddF(&hsum[j], v);
        atomAddF(&hsq[j], u);
      }
    }
}

// ---------------- fold BN stats (sum/sumsq of h) + w2 into (W2p, b2p) ----------------
__global__ __launch_bounds__(256) void kbnfold(const float* __restrict__ hsum,
    const float* __restrict__ hsq, float invN, const float* __restrict__ w2,
    const float* __restrict__ b2, float* __restrict__ W2p, float* __restrict__ b2p){
  __shared__ float mu[EMB], istd[EMB];
  int t = threadIdx.x;
  if (t < EMB){
    float m = hsum[t] * invN;
    float var = hsq[t] * invN - m * m;
    mu[t] = m; istd[t] = 1.0f / sqrtf(var + BNEPS);
  }
  __syncthreads();
  for (int e = t; e < EMB * EMB; e += 256){
    int k = e >> 6;
    W2p[e] = istd[k] * w2[e];
  }
  if (t < EMB){
    float acc = b2[t];
    for (int k = 0; k < EMB; k++) acc -= mu[k] * istd[k] * w2[k * EMB + t];
    b2p[t] = acc;
  }
}

// ---------------- MFMA pass 2: msg = relu(h@W2p+b2p); agg[dst] += msg ----------------
__global__ __launch_bounds__(256) void kpass2m(const u16* __restrict__ hbf,
    const int* __restrict__ dstv, const float* __restrict__ W2p,
    const float* __restrict__ b2p, int ntiles, float* __restrict__ agg){
  int t = threadIdx.x, l = t & 63, wv = t >> 6, g = l >> 4, e16 = l & 15;
  // W2 frags with pi row permutation
  bf16x8 w2f[4][2];
  #pragma unroll
  for (int nb = 0; nb < 4; nb++)
    #pragma unroll
    for (int kf = 0; kf < 2; kf++)
      #pragma unroll
      for (int i = 0; i < 8; i++){
        int row = (kf + 2*(i>>2))*16 + g*4 + (i&3);            // sigma(k3)
        w2f[nb][kf][i] = (short)f2bf(W2p[row * EMB + nb*16 + e16]);
      }
  float bv[4];
  #pragma unroll
  for (int nb = 0; nb < 4; nb++) bv[nb] = b2p[nb*16 + e16];

  int gw = blockIdx.x * 4 + wv, nw = gridDim.x * 4;
  for (int T = gw; T < ntiles; T += nw){
    bf16x8 h0 = *(const bf16x8*)(hbf + ((size_t)(T*2 + 0) * 64 + l) * 8);
    bf16x8 h1 = *(const bf16x8*)(hbf + ((size_t)(T*2 + 1) * 64 + l) * 8);
    f32x4 C[4];
    #pragma unroll
    for (int nb = 0; nb < 4; nb++) C[nb] = (f32x4){bv[nb], bv[nb], bv[nb], bv[nb]};
    #pragma unroll
    for (int nb = 0; nb < 4; nb++){
      C[nb] = __builtin_amdgcn_mfma_f32_16x16x32_bf16(h0, w2f[nb][0], C[nb], 0, 0, 0);
      C[nb] = __builtin_amdgcn_mfma_f32_16x16x32_bf16(h1, w2f[nb][1], C[nb], 0, 0, 0);
    }
    // lane holds msg[e = g*4+reg][jo = nb*16+e16]
    #pragma unroll
    for (int r = 0; r < 4; r++){
      int d = dstv[T*16 + g*4 + r];
      float* ap = agg + (size_t)d * EMB + e16;
      #pragma unroll
      for (int nb = 0; nb < 4; nb++)
        atomAddF(ap + nb*16, fmaxf(C[nb][r], 0.f));
    }
  }
}

// ---------------- output stage 1 ----------------
__global__ __launch_bounds__(256) void kout1(const float* __restrict__ agg,
    const int* __restrict__ cnt, const float* __restrict__ right,
    const float* __restrict__ ow1, const float* __restrict__ ob1, int N,
    float* __restrict__ h_o, float* __restrict__ osum, float* __restrict__ osq){
  __shared__ float xs[4][2 * EMB];
  __shared__ float bsh[EMB];
  __shared__ float red[256];
  int t = threadIdx.x, r = t >> 6, j = t & 63;
  float wc[2 * EMB];
  #pragma unroll
  for (int k = 0; k < 2 * EMB; k++) wc[k] = ow1[k * EMB + j];
  if (t < EMB) bsh[t] = ob1[t];
  __syncthreads();
  float psum = 0.f, psq = 0.f;
  for (int n0 = blockIdx.x * 4; n0 < N; n0 += gridDim.x * 4){
    int n = n0 + r; bool ok = n < N;
    if (ok){
      float c = fmaxf((float)cnt[n], 1.f);
      xs[r][j] = agg[(size_t)n * EMB + j] / c;
      xs[r][EMB + j] = right[(size_t)n * EMB + j];
    } else { xs[r][j] = 0.f; xs[r][EMB + j] = 0.f; }
    __syncthreads();
    float a0 = bsh[j], a1 = 0.f, a2 = 0.f, a3 = 0.f;
    const float4* x4 = (const float4*)xs[r];
    #pragma unroll
    for (int kb = 0; kb < 32; kb++){
      float4 v = x4[kb];
      a0 += v.x * wc[4*kb]; a1 += v.y * wc[4*kb+1];
      a2 += v.z * wc[4*kb+2]; a3 += v.w * wc[4*kb+3];
    }
    if (ok){
      float h = (a0 + a1) + (a2 + a3);
      h_o[(size_t)n * EMB + j] = h;
      psum += h; psq += h * h;
    }
    __syncthreads();
  }
  red[t] = psum; __syncthreads();
  if (t < EMB) atomAddF(&osum[t], red[t] + red[t + 64] + red[t + 128] + red[t + 192]);
  __syncthreads();
  red[t] = psq; __syncthreads();
  if (t < EMB) atomAddF(&osq[t], red[t] + red[t + 64] + red[t + 128] + red[t + 192]);
}

// ---------------- output stage 2 ----------------
__global__ __launch_bounds__(256) void kout2(const float* __restrict__ h_o,
    const float* __restrict__ W2o, const float* __restrict__ b2o, int N,
    float* __restrict__ out){
  __shared__ float hs[4][EMB];
  __shared__ float bsh[EMB];
  int t = threadIdx.x, r = t >> 6, j = t & 63;
  float wc[EMB];
  #pragma unroll
  for (int k = 0; k < EMB; k++) wc[k] = W2o[k * EMB + j];
  if (t < EMB) bsh[t] = b2o[t];
  __syncthreads();
  for (int n0 = blockIdx.x * 4; n0 < N; n0 += gridDim.x * 4){
    int n = n0 + r; bool ok = n < N;
    hs[r][j] = ok ? h_o[(size_t)n * EMB + j] : 0.f;
    __syncthreads();
    float a0 = bsh[j], a1 = 0.f, a2 = 0.f, a3 = 0.f;
    const float4* h4 = (const float4*)hs[r];
    #pragma unroll
    for (int kb = 0; kb < 16; kb++){
      float4 v = h4[kb];
      a0 += v.x * wc[4*kb]; a1 += v.y * wc[4*kb+1];
      a2 += v.z * wc[4*kb+2]; a3 += v.w * wc[4*kb+3];
    }
    if (ok) out[(size_t)n * EMB + j] = fmaxf((a0 + a1) + (a2 + a3), 0.f);
    __syncthreads();
  }
}

extern "C" void kernel_launch(void* const* d_in, const int* in_sizes, int n_in,
                              void* d_out, int out_size, void* d_ws, size_t ws_size,
                              hipStream_t stream){
  const float* left   = (const float*)d_in[0];
  const float* right  = (const float*)d_in[1];
  const float* edgef  = (const float*)d_in[2];
  const int*   eidx   = (const int*)d_in[3];
  const float* fmr_w1 = (const float*)d_in[4];  const float* fmr_b1 = (const float*)d_in[5];
  const float* fmr_w2 = (const float*)d_in[6];  const float* fmr_b2 = (const float*)d_in[7];
  const float* fme_w1 = (const float*)d_in[8];  const float* fme_b1 = (const float*)d_in[9];
  const float* fme_w2 = (const float*)d_in[10]; const float* fme_b2 = (const float*)d_in[11];
  const float* fmf_w1 = (const float*)d_in[12]; const float* fmf_b1 = (const float*)d_in[13];
  const float* fmf_w2 = (const float*)d_in[14]; const float* fmf_b2 = (const float*)d_in[15];
  const float* ow1    = (const float*)d_in[16]; const float* ob1    = (const float*)d_in[17];
  const float* ow2    = (const float*)d_in[18]; const float* ob2    = (const float*)d_in[19];

  int NL = in_sizes[0] / EMB;
  int NR = in_sizes[1] / EMB;
  int E  = in_sizes[2] / EMB;
  const int* srcv = eidx;
  const int* dstv = eidx + E;

  char* base = (char*)d_ws;
  size_t o = 0;
  u16* hbf = (u16*)(base + o);      o += (size_t)E * EMB * sizeof(u16);
  float* P_i  = (float*)(base + o); o += (size_t)NR * EMB * 4;
  float* P_j  = (float*)(base + o); o += (size_t)NL * EMB * 4;
  float* h_o  = (float*)(base + o); o += (size_t)NR * EMB * 4;
  float* Weff_i = (float*)(base + o); o += EMB * EMB * 4;
  float* beff_i = (float*)(base + o); o += EMB * 4;
  float* Weff_j = (float*)(base + o); o += EMB * EMB * 4;
  float* beff_j = (float*)(base + o); o += EMB * 4;
  float* Weff_e = (float*)(base + o); o += EMB * EMB * 4;
  float* beff_e = (float*)(base + o); o += EMB * 4;
  float* W2p  = (float*)(base + o); o += EMB * EMB * 4;
  float* b2p  = (float*)(base + o); o += EMB * 4;
  float* W2o  = (float*)(base + o); o += EMB * EMB * 4;
  float* b2o  = (float*)(base + o); o += EMB * 4;
  // ---- zeroed region starts here ----
  char* zstart = base + o;
  float* agg     = (float*)(base + o); o += (size_t)NR * EMB * 4;
  int* cnt_dst   = (int*)(base + o);   o += (size_t)NR * 4;
  int* cnt_src   = (int*)(base + o);   o += (size_t)NL * 4;
  float* musum_i = (float*)(base + o); o += EMB * 4;
  float* S_i     = (float*)(base + o); o += EMB * EMB * 4;
  float* musum_j = (float*)(base + o); o += EMB * 4;
  float* S_j     = (float*)(base + o); o += EMB * EMB * 4;
  float* musum_e = (float*)(base + o); o += EMB * 4;
  float* S_e     = (float*)(base + o); o += EMB * EMB * 4;
  float* hsum    = (float*)(base + o); o += EMB * 4;
  float* hsq     = (float*)(base + o); o += EMB * 4;
  float* osum    = (float*)(base + o); o += EMB * 4;
  float* osq     = (float*)(base + o); o += EMB * 4;
  int zn = (int)(((base + o) - zstart) / 4);

  float invE = 1.0f / (float)E;
  float invNR = 1.0f / (float)NR;
  int ntE = E >> 4;   // 16-edge tiles (E % 16 == 0 for this workload)

  kzero<<<512, 256, 0, stream>>>((float*)zstart, zn);
  kcount<<<512, 256, 0, stream>>>(srcv, dstv, E, cnt_src, cnt_dst);
  kprepm<<<1024, 256, 0, stream>>>(edgef, E, musum_e, S_e);
  kgram<<<256, 256, 0, stream>>>(right, cnt_dst, NR, musum_i, S_i);
  kgram<<<256, 256, 0, stream>>>(left,  cnt_src, NL, musum_j, S_j);
  keffw<<<1, 256, 0, stream>>>(musum_i, S_i, fmr_w1, fmr_b1, fmr_w2, fmr_b2, invE, Weff_i, beff_i);
  keffw<<<1, 256, 0, stream>>>(musum_j, S_j, fmr_w1, fmr_b1, fmr_w2, fmr_b2, invE, Weff_j, beff_j);
  keffw<<<1, 256, 0, stream>>>(musum_e, S_e, fme_w1, fme_b1, fme_w2, fme_b2, invE, Weff_e, beff_e);
  knodeMP<<<1024, 256, 0, stream>>>(right, Weff_i, beff_i, fmf_w1,                 NR, P_i);
  knodeMP<<<1024, 256, 0, stream>>>(left,  Weff_j, beff_j, fmf_w1 + 2 * EMB * EMB, NL, P_j);
  kpass1m<<<2048, 256, 0, stream>>>(edgef, srcv, dstv, Weff_e, beff_e,
                                    fmf_w1 + EMB * EMB, fmf_b1, P_i, P_j, ntE, hbf, hsum, hsq);
  kbnfold<<<1, 256, 0, stream>>>(hsum, hsq, invE, fmf_w2, fmf_b2, W2p, b2p);
  kpass2m<<<2048, 256, 0, stream>>>(hbf, dstv, W2p, b2p, ntE, agg);
  kout1<<<1024, 256, 0, stream>>>(agg, cnt_dst, right, ow1, ob1, NR, h_o, osum, osq);
  kbnfold<<<1, 256, 0, stream>>>(osum, osq, invNR, ow2, ob2, W2o, b2o);
  kout2<<<1024, 256, 0, stream>>>(h_o, W2o, b2o, NR, (float*)d_out);
}

// Round 3
// 1459.449 us; speedup vs baseline: 1.6620x; 1.2499x over previous
//
#include <hip/hip_runtime.h>

#define EMB 64
#define BNEPS 1e-5f

typedef unsigned short u16;
typedef float f32x4 __attribute__((ext_vector_type(4)));
typedef short bf16x8 __attribute__((ext_vector_type(8)));

__device__ __forceinline__ float bf2f(u16 u){
  union { unsigned int i; float f; } v; v.i = ((unsigned int)u) << 16; return v.f;
}
__device__ __forceinline__ u16 f2bf(float x){
  union { float f; unsigned int i; } v; v.f = x;
  unsigned int r = v.i + 0x7FFFu + ((v.i >> 16) & 1u);   // RNE
  return (u16)(r >> 16);
}
__device__ __forceinline__ void atomAddF(float* p, float v){
  __hip_atomic_fetch_add(p, v, __ATOMIC_RELAXED, __HIP_MEMORY_SCOPE_AGENT);
}

// ---------------- zero scratch ----------------
__global__ void kzero(float* __restrict__ p, int n){
  int i = blockIdx.x * blockDim.x + threadIdx.x;
  int st = gridDim.x * blockDim.x;
  for (; i < n; i += st) p[i] = 0.f;
}

// ---------------- per-node edge-endpoint counts ----------------
__global__ void kcount(const int* __restrict__ src, const int* __restrict__ dst,
                       int E, int* __restrict__ cs, int* __restrict__ cd){
  int i = blockIdx.x * blockDim.x + threadIdx.x;
  int st = gridDim.x * blockDim.x;
  for (; i < E; i += st){
    atomicAdd(&cd[dst[i]], 1);
    atomicAdd(&cs[src[i]], 1);
  }
}

// ---------------- (weighted) column-mean + Gram of rows (node-scale, fp32) ----------------
__global__ __launch_bounds__(256) void kgram(const float* __restrict__ X,
    const int* __restrict__ cnt, int N,
    float* __restrict__ musum, float* __restrict__ S){
  __shared__ float xs[4][EMB];
  __shared__ float cs[4];
  int t = threadIdx.x, r = t >> 6, j = t & 63;
  int a = t >> 2, bb = (t & 3) << 4;
  float g[16];
  #pragma unroll
  for (int i = 0; i < 16; i++) g[i] = 0.f;
  float mup = 0.f;
  for (int n0 = blockIdx.x * 4; n0 < N; n0 += gridDim.x * 4){
    int n = n0 + r; bool ok = n < N;
    xs[r][j] = ok ? X[(size_t)n * EMB + j] : 0.f;
    if (j == 0) cs[r] = ok ? (cnt ? (float)cnt[n] : 1.f) : 0.f;
    __syncthreads();
    #pragma unroll
    for (int rr = 0; rr < 4; rr++){
      float xa = cs[rr] * xs[rr][a];
      const float4* x4 = (const float4*)&xs[rr][bb];
      #pragma unroll
      for (int i4 = 0; i4 < 4; i4++){
        float4 v = x4[i4];
        g[4*i4+0] += xa * v.x; g[4*i4+1] += xa * v.y;
        g[4*i4+2] += xa * v.z; g[4*i4+3] += xa * v.w;
      }
    }
    if (t < EMB) mup += cs[0]*xs[0][t] + cs[1]*xs[1][t] + cs[2]*xs[2][t] + cs[3]*xs[3][t];
    __syncthreads();
  }
  #pragma unroll
  for (int i = 0; i < 16; i++) atomAddF(&S[a * EMB + bb + i], g[i]);
  if (t < EMB) atomAddF(&musum[t], mup);
}

// ---------------- MFMA Gram + column means over edge features ----------------
__global__ __launch_bounds__(256) void kprepm(const float* __restrict__ XE, int N,
    float* __restrict__ musum, float* __restrict__ S){
  __shared__ __align__(16) u16 XT[64 * 72];
  int t = threadIdx.x, l = t & 63, wv = t >> 6, g = l >> 4, e16 = l & 15;
  f32x4 C[4];
  #pragma unroll
  for (int mb = 0; mb < 4; mb++) C[mb] = (f32x4){0.f,0.f,0.f,0.f};
  float ms[4] = {0.f, 0.f, 0.f, 0.f};
  int ntiles = N >> 6;
  for (int T = blockIdx.x; T < ntiles; T += gridDim.x){
    __syncthreads();
    #pragma unroll
    for (int i = 0; i < 4; i++){
      int c = t + i * 256;
      int row = c >> 4, k0 = (c & 15) << 2;
      f32x4 v = *(const f32x4*)(XE + ((size_t)T * 64 + row) * EMB + k0);
      #pragma unroll
      for (int q = 0; q < 4; q++){
        ms[q] += v[q];
        XT[(k0 + q) * 72 + row] = f2bf(v[q]);
      }
    }
    __syncthreads();
    #pragma unroll
    for (int kf = 0; kf < 2; kf++){
      bf16x8 fr[4];
      #pragma unroll
      for (int mb = 0; mb < 4; mb++)
        fr[mb] = *(const bf16x8*)&XT[(mb*16 + e16) * 72 + kf*32 + g*8];
      bf16x8 bfr = *(const bf16x8*)&XT[(wv*16 + e16) * 72 + kf*32 + g*8];
      #pragma unroll
      for (int mb = 0; mb < 4; mb++)
        C[mb] = __builtin_amdgcn_mfma_f32_16x16x32_bf16(fr[mb], bfr, C[mb], 0, 0, 0);
    }
  }
  #pragma unroll
  for (int mb = 0; mb < 4; mb++)
    #pragma unroll
    for (int r = 0; r < 4; r++)
      atomAddF(&S[(mb*16 + g*4 + r) * EMB + wv*16 + e16], C[mb][r]);
  __syncthreads();
  float* red = (float*)XT;
  #pragma unroll
  for (int q = 0; q < 4; q++){
    float x = ms[q];
    x += __shfl_xor(x, 16); x += __shfl_xor(x, 32);
    if (l < 16) red[(wv*16 + l)*4 + q] = x;
  }
  __syncthreads();
  if (t < 64){
    int k = t >> 2, q = t & 3;
    float s = red[(k)*4+q] + red[(16+k)*4+q] + red[(32+k)*4+q] + red[(48+k)*4+q];
    atomAddF(&musum[k*4 + q], s);
  }
}

// ---------------- fold BN(stats of h=x@w1+b1) + w2 into (Weff, beff) ----------------
__global__ __launch_bounds__(256) void keffw(const float* __restrict__ musum,
    const float* __restrict__ S, const float* __restrict__ w1, const float* __restrict__ b1,
    const float* __restrict__ w2, const float* __restrict__ b2, float invN,
    float* __restrict__ Weff, float* __restrict__ beff){
  __shared__ float mu[EMB];
  __shared__ float C[EMB][EMB];
  __shared__ float W1p[EMB][EMB + 1];
  __shared__ float c1[EMB];
  __shared__ float istd[EMB];
  __shared__ float red[256];
  int t = threadIdx.x;
  if (t < EMB) mu[t] = musum[t] * invN;
  __syncthreads();
  for (int e = t; e < EMB * EMB; e += 256){
    int k = e >> 6, l = e & 63;
    C[k][l] = S[e] * invN - mu[k] * mu[l];
  }
  __syncthreads();
  {
    int j = t & 63, kg = t >> 6;
    float part = 0.f;
    for (int k = kg * 16; k < kg * 16 + 16; k++){
      float inner = 0.f;
      for (int l = 0; l < EMB; l++) inner += C[k][l] * w1[l * EMB + j];
      part += w1[k * EMB + j] * inner;
    }
    red[t] = part;
  }
  __syncthreads();
  if (t < EMB){
    float var = red[t] + red[t + 64] + red[t + 128] + red[t + 192];
    float is = 1.0f / sqrtf(var + BNEPS);
    istd[t] = is;
    float muh = 0.f;
    for (int k = 0; k < EMB; k++) muh += mu[k] * w1[k * EMB + t];
    muh += b1[t];
    c1[t] = (b1[t] - muh) * is;
  }
  __syncthreads();
  for (int e = t; e < EMB * EMB; e += 256){
    int k = e >> 6, j = e & 63;
    W1p[k][j] = w1[e] * istd[j];
  }
  __syncthreads();
  {
    int k = t >> 2, j2b = (t & 3) << 4;
    float acc[16];
    #pragma unroll
    for (int i = 0; i < 16; i++) acc[i] = 0.f;
    for (int j = 0; j < EMB; j++){
      float wp = W1p[k][j];
      const float* w2r = &w2[j * EMB + j2b];
      #pragma unroll
      for (int i = 0; i < 16; i++) acc[i] += wp * w2r[i];
    }
    #pragma unroll
    for (int i = 0; i < 16; i++) Weff[k * EMB + j2b + i] = acc[i];
  }
  if (t < EMB){
    float acc = b2[t];
    for (int j = 0; j < EMB; j++) acc += c1[j] * w2[j * EMB + t];
    beff[t] = acc;
  }
}

// ---------------- weight -> frag-major bf16 (coalesced prologue for MFMA kernels) ----------------
// F[((mb*2+kf)*64 + l)*8 + i] = bf16(W[row*64 + mb*16 + e16]),
// row = std: kf*32+g*8+i  |  pi: (kf+2*(i>>2))*16 + g*4 + (i&3)
__global__ void kfrag(const float* __restrict__ W, u16* __restrict__ F, int pi){
  int t = threadIdx.x;
  for (int ent = t; ent < 512; ent += 256){
    int mb = ent >> 7, kf = (ent >> 6) & 1, l = ent & 63;
    int g = (l >> 4), e16 = l & 15;
    u16 out[8];
    #pragma unroll
    for (int i = 0; i < 8; i++){
      int row = pi ? ((kf + 2*(i>>2))*16 + g*4 + (i&3)) : (kf*32 + g*8 + i);
      out[i] = f2bf(W[row * EMB + mb*16 + e16]);
    }
    *(bf16x8*)(F + ent * 8) = *(bf16x8*)out;
  }
}

// ---------------- per-node: P = relu(x@Weff+beff) @ Wslice ----------------
__global__ __launch_bounds__(256) void knodeMP(const float* __restrict__ X,
    const float* __restrict__ Weff, const float* __restrict__ beff,
    const float* __restrict__ Wslice, int N, float* __restrict__ P){
  __shared__ float xs[4][EMB];
  __shared__ float ms[4][EMB];
  __shared__ float be[EMB];
  int t = threadIdx.x, r = t >> 6, j = t & 63;
  float wA[EMB], wB[EMB];
  #pragma unroll
  for (int k = 0; k < EMB; k++){ wA[k] = Weff[k * EMB + j]; wB[k] = Wslice[k * EMB + j]; }
  if (t < EMB) be[t] = beff[t];
  __syncthreads();
  for (int n0 = blockIdx.x * 4; n0 < N; n0 += gridDim.x * 4){
    int n = n0 + r; bool ok = n < N;
    xs[r][j] = ok ? X[(size_t)n * EMB + j] : 0.f;
    __syncthreads();
    float a0 = be[j], a1 = 0.f, a2 = 0.f, a3 = 0.f;
    const float4* x4 = (const float4*)xs[r];
    #pragma unroll
    for (int kb = 0; kb < 16; kb++){
      float4 v = x4[kb];
      a0 += v.x * wA[4*kb]; a1 += v.y * wA[4*kb+1];
      a2 += v.z * wA[4*kb+2]; a3 += v.w * wA[4*kb+3];
    }
    ms[r][j] = fmaxf((a0 + a1) + (a2 + a3), 0.f);
    __syncthreads();
    float p0 = 0.f, p1 = 0.f, p2 = 0.f, p3 = 0.f;
    const float4* m4 = (const float4*)ms[r];
    #pragma unroll
    for (int kb = 0; kb < 16; kb++){
      float4 v = m4[kb];
      p0 += v.x * wB[4*kb]; p1 += v.y * wB[4*kb+1];
      p2 += v.z * wB[4*kb+2]; p3 += v.w * wB[4*kb+3];
    }
    if (ok) P[(size_t)n * EMB + j] = (p0 + p1) + (p2 + p3);
    __syncthreads();
  }
}

// ---------------- MFMA pass 1 (vectorized gathers, coalesced frag preload) ----------------
__global__ __launch_bounds__(256) void kpass1m(const float* __restrict__ XE,
    const int* __restrict__ srcv, const int* __restrict__ dstv,
    const u16* __restrict__ fragA1, const u16* __restrict__ fragA2,
    const float* __restrict__ beff_e, const float* __restrict__ bf1,
    const float* __restrict__ P_i, const float* __restrict__ P_j, int ntiles,
    u16* __restrict__ hbf, float* __restrict__ hsum, float* __restrict__ hsq){
  int t = threadIdx.x, l = t & 63, wv = t >> 6, g = l >> 4, e16 = l & 15;
  bf16x8 a1w[4][2], a2w[4][2];
  #pragma unroll
  for (int mb = 0; mb < 4; mb++)
    #pragma unroll
    for (int kf = 0; kf < 2; kf++){
      a1w[mb][kf] = *(const bf16x8*)(fragA1 + ((size_t)((mb*2+kf)*64 + l)) * 8);
      a2w[mb][kf] = *(const bf16x8*)(fragA2 + ((size_t)((mb*2+kf)*64 + l)) * 8);
    }
  f32x4 b1v[4], b2v[4];
  #pragma unroll
  for (int mb = 0; mb < 4; mb++)
    #pragma unroll
    for (int r = 0; r < 4; r++){
      b1v[mb][r] = beff_e[mb*16 + g*4 + r];
      b2v[mb][r] = bf1[mb*16 + g*4 + r];
    }
  f32x4 ps[4], pq[4];
  #pragma unroll
  for (int mb = 0; mb < 4; mb++){ ps[mb] = (f32x4){0,0,0,0}; pq[mb] = (f32x4){0,0,0,0}; }

  int gw = blockIdx.x * 4 + wv, nw = gridDim.x * 4;
  int d_n = 0, s_n = 0;
  if (gw < ntiles){ d_n = dstv[gw*16 + e16]; s_n = srcv[gw*16 + e16]; }
  for (int T = gw; T < ntiles; T += nw){
    int d = d_n, s = s_n;
    const float* xr = XE + (size_t)(T*16 + e16) * EMB;
    f32x4 x0 = *(const f32x4*)(xr + g*8);
    f32x4 x1 = *(const f32x4*)(xr + g*8 + 4);
    f32x4 x2 = *(const f32x4*)(xr + 32 + g*8);
    f32x4 x3 = *(const f32x4*)(xr + 36 + g*8);
    // vectorized P gathers: lane (g,e16) takes P[d][mb*16+g*4 .. +3]
    const f32x4* pid4 = (const f32x4*)(P_i + (size_t)d * EMB);
    const f32x4* pjs4 = (const f32x4*)(P_j + (size_t)s * EMB);
    f32x4 pi4[4], pj4[4];
    #pragma unroll
    for (int mb = 0; mb < 4; mb++){ pi4[mb] = pid4[mb*4 + g]; pj4[mb] = pjs4[mb*4 + g]; }
    // prefetch next tile's indices (breaks idx->gather serial chain)
    int T2 = T + nw;
    if (T2 < ntiles){ d_n = dstv[T2*16 + e16]; s_n = srcv[T2*16 + e16]; }
    // init layer2 accum with bias + P gathers
    f32x4 C2[4];
    #pragma unroll
    for (int mb = 0; mb < 4; mb++) C2[mb] = b2v[mb] + pi4[mb] + pj4[mb];
    // X frags
    bf16x8 xf0, xf1;
    #pragma unroll
    for (int q = 0; q < 4; q++){
      xf0[q]   = (short)f2bf(x0[q]); xf0[4+q] = (short)f2bf(x1[q]);
      xf1[q]   = (short)f2bf(x2[q]); xf1[4+q] = (short)f2bf(x3[q]);
    }
    // layer 1 (transposed)
    f32x4 C1[4];
    #pragma unroll
    for (int mb = 0; mb < 4; mb++) C1[mb] = b1v[mb];
    #pragma unroll
    for (int mb = 0; mb < 4; mb++){
      C1[mb] = __builtin_amdgcn_mfma_f32_16x16x32_bf16(a1w[mb][0], xf0, C1[mb], 0, 0, 0);
      C1[mb] = __builtin_amdgcn_mfma_f32_16x16x32_bf16(a1w[mb][1], xf1, C1[mb], 0, 0, 0);
    }
    // relu + pack into layer2 A-frags via pi
    bf16x8 mfr0, mfr1;
    #pragma unroll
    for (int q = 0; q < 4; q++){
      mfr0[q]   = (short)f2bf(fmaxf(C1[0][q], 0.f));
      mfr0[4+q] = (short)f2bf(fmaxf(C1[2][q], 0.f));
      mfr1[q]   = (short)f2bf(fmaxf(C1[1][q], 0.f));
      mfr1[4+q] = (short)f2bf(fmaxf(C1[3][q], 0.f));
    }
    // layer 2 (transposed)
    #pragma unroll
    for (int mb = 0; mb < 4; mb++){
      C2[mb] = __builtin_amdgcn_mfma_f32_16x16x32_bf16(a2w[mb][0], mfr0, C2[mb], 0, 0, 0);
      C2[mb] = __builtin_amdgcn_mfma_f32_16x16x32_bf16(a2w[mb][1], mfr1, C2[mb], 0, 0, 0);
    }
    #pragma unroll
    for (int mb = 0; mb < 4; mb++){ ps[mb] += C2[mb]; pq[mb] += C2[mb] * C2[mb]; }
    bf16x8 h0, h1;
    #pragma unroll
    for (int q = 0; q < 4; q++){
      h0[q]   = (short)f2bf(C2[0][q]); h0[4+q] = (short)f2bf(C2[2][q]);
      h1[q]   = (short)f2bf(C2[1][q]); h1[4+q] = (short)f2bf(C2[3][q]);
    }
    *(bf16x8*)(hbf + ((size_t)(T*2 + 0) * 64 + l) * 8) = h0;
    *(bf16x8*)(hbf + ((size_t)(T*2 + 1) * 64 + l) * 8) = h1;
  }
  #pragma unroll
  for (int mb = 0; mb < 4; mb++)
    #pragma unroll
    for (int r = 0; r < 4; r++){
      float v = ps[mb][r], u = pq[mb][r];
      #pragma unroll
      for (int m = 1; m < 16; m <<= 1){ v += __shfl_xor(v, m); u += __shfl_xor(u, m); }
      if (e16 == 0){
        int j = mb*16 + g*4 + r;
        atomAddF(&hsum[j], v);
        atomAddF(&hsq[j], u);
      }
    }
}

// ---------------- fold BN stats (sum/sumsq of h) + w2 into (W2p, b2p) ----------------
__global__ __launch_bounds__(256) void kbnfold(const float* __restrict__ hsum,
    const float* __restrict__ hsq, float invN, const float* __restrict__ w2,
    const float* __restrict__ b2, float* __restrict__ W2p, float* __restrict__ b2p){
  __shared__ float mu[EMB], istd[EMB];
  int t = threadIdx.x;
  if (t < EMB){
    float m = hsum[t] * invN;
    float var = hsq[t] * invN - m * m;
    mu[t] = m; istd[t] = 1.0f / sqrtf(var + BNEPS);
  }
  __syncthreads();
  for (int e = t; e < EMB * EMB; e += 256){
    int k = e >> 6;
    W2p[e] = istd[k] * w2[e];
  }
  if (t < EMB){
    float acc = b2[t];
    for (int k = 0; k < EMB; k++) acc -= mu[k] * istd[k] * w2[k * EMB + t];
    b2p[t] = acc;
  }
}

// ---------------- MFMA pass 2: msg = relu(h@W2p+b2p); agg[dst] += msg ----------------
__global__ __launch_bounds__(256) void kpass2m(const u16* __restrict__ hbf,
    const int* __restrict__ dstv, const u16* __restrict__ fragW2,
    const float* __restrict__ b2p, int ntiles, float* __restrict__ agg){
  int t = threadIdx.x, l = t & 63, wv = t >> 6, g = l >> 4, e16 = l & 15;
  bf16x8 w2f[4][2];
  #pragma unroll
  for (int nb = 0; nb < 4; nb++)
    #pragma unroll
    for (int kf = 0; kf < 2; kf++)
      w2f[nb][kf] = *(const bf16x8*)(fragW2 + ((size_t)((nb*2+kf)*64 + l)) * 8);
  float bv[4];
  #pragma unroll
  for (int nb = 0; nb < 4; nb++) bv[nb] = b2p[nb*16 + e16];

  int gw = blockIdx.x * 4 + wv, nw = gridDim.x * 4;
  for (int T = gw; T < ntiles; T += nw){
    bf16x8 h0 = *(const bf16x8*)(hbf + ((size_t)(T*2 + 0) * 64 + l) * 8);
    bf16x8 h1 = *(const bf16x8*)(hbf + ((size_t)(T*2 + 1) * 64 + l) * 8);
    int4 dd = *(const int4*)(dstv + T*16 + g*4);
    int dr[4] = {dd.x, dd.y, dd.z, dd.w};
    f32x4 C[4];
    #pragma unroll
    for (int nb = 0; nb < 4; nb++) C[nb] = (f32x4){bv[nb], bv[nb], bv[nb], bv[nb]};
    #pragma unroll
    for (int nb = 0; nb < 4; nb++){
      C[nb] = __builtin_amdgcn_mfma_f32_16x16x32_bf16(h0, w2f[nb][0], C[nb], 0, 0, 0);
      C[nb] = __builtin_amdgcn_mfma_f32_16x16x32_bf16(h1, w2f[nb][1], C[nb], 0, 0, 0);
    }
    #pragma unroll
    for (int r = 0; r < 4; r++){
      float* ap = agg + (size_t)dr[r] * EMB + e16;
      #pragma unroll
      for (int nb = 0; nb < 4; nb++)
        atomAddF(ap + nb*16, fmaxf(C[nb][r], 0.f));
    }
  }
}

// ---------------- output stage 1 ----------------
__global__ __launch_bounds__(256) void kout1(const float* __restrict__ agg,
    const int* __restrict__ cnt, const float* __restrict__ right,
    const float* __restrict__ ow1, const float* __restrict__ ob1, int N,
    float* __restrict__ h_o, float* __restrict__ osum, float* __restrict__ osq){
  __shared__ float xs[4][2 * EMB];
  __shared__ float bsh[EMB];
  __shared__ float red[256];
  int t = threadIdx.x, r = t >> 6, j = t & 63;
  float wc[2 * EMB];
  #pragma unroll
  for (int k = 0; k < 2 * EMB; k++) wc[k] = ow1[k * EMB + j];
  if (t < EMB) bsh[t] = ob1[t];
  __syncthreads();
  float psum = 0.f, psq = 0.f;
  for (int n0 = blockIdx.x * 4; n0 < N; n0 += gridDim.x * 4){
    int n = n0 + r; bool ok = n < N;
    if (ok){
      float c = fmaxf((float)cnt[n], 1.f);
      xs[r][j] = agg[(size_t)n * EMB + j] / c;
      xs[r][EMB + j] = right[(size_t)n * EMB + j];
    } else { xs[r][j] = 0.f; xs[r][EMB + j] = 0.f; }
    __syncthreads();
    float a0 = bsh[j], a1 = 0.f, a2 = 0.f, a3 = 0.f;
    const float4* x4 = (const float4*)xs[r];
    #pragma unroll
    for (int kb = 0; kb < 32; kb++){
      float4 v = x4[kb];
      a0 += v.x * wc[4*kb]; a1 += v.y * wc[4*kb+1];
      a2 += v.z * wc[4*kb+2]; a3 += v.w * wc[4*kb+3];
    }
    if (ok){
      float h = (a0 + a1) + (a2 + a3);
      h_o[(size_t)n * EMB + j] = h;
      psum += h; psq += h * h;
    }
    __syncthreads();
  }
  red[t] = psum; __syncthreads();
  if (t < EMB) atomAddF(&osum[t], red[t] + red[t + 64] + red[t + 128] + red[t + 192]);
  __syncthreads();
  red[t] = psq; __syncthreads();
  if (t < EMB) atomAddF(&osq[t], red[t] + red[t + 64] + red[t + 128] + red[t + 192]);
}

// ---------------- output stage 2 ----------------
__global__ __launch_bounds__(256) void kout2(const float* __restrict__ h_o,
    const float* __restrict__ W2o, const float* __restrict__ b2o, int N,
    float* __restrict__ out){
  __shared__ float hs[4][EMB];
  __shared__ float bsh[EMB];
  int t = threadIdx.x, r = t >> 6, j = t & 63;
  float wc[EMB];
  #pragma unroll
  for (int k = 0; k < EMB; k++) wc[k] = W2o[k * EMB + j];
  if (t < EMB) bsh[t] = b2o[t];
  __syncthreads();
  for (int n0 = blockIdx.x * 4; n0 < N; n0 += gridDim.x * 4){
    int n = n0 + r; bool ok = n < N;
    hs[r][j] = ok ? h_o[(size_t)n * EMB + j] : 0.f;
    __syncthreads();
    float a0 = bsh[j], a1 = 0.f, a2 = 0.f, a3 = 0.f;
    const float4* h4 = (const float4*)hs[r];
    #pragma unroll
    for (int kb = 0; kb < 16; kb++){
      float4 v = h4[kb];
      a0 += v.x * wc[4*kb]; a1 += v.y * wc[4*kb+1];
      a2 += v.z * wc[4*kb+2]; a3 += v.w * wc[4*kb+3];
    }
    if (ok) out[(size_t)n * EMB + j] = fmaxf((a0 + a1) + (a2 + a3), 0.f);
    __syncthreads();
  }
}

extern "C" void kernel_launch(void* const* d_in, const int* in_sizes, int n_in,
                              void* d_out, int out_size, void* d_ws, size_t ws_size,
                              hipStream_t stream){
  const float* left   = (const float*)d_in[0];
  const float* right  = (const float*)d_in[1];
  const float* edgef  = (const float*)d_in[2];
  const int*   eidx   = (const int*)d_in[3];
  const float* fmr_w1 = (const float*)d_in[4];  const float* fmr_b1 = (const float*)d_in[5];
  const float* fmr_w2 = (const float*)d_in[6];  const float* fmr_b2 = (const float*)d_in[7];
  const float* fme_w1 = (const float*)d_in[8];  const float* fme_b1 = (const float*)d_in[9];
  const float* fme_w2 = (const float*)d_in[10]; const float* fme_b2 = (const float*)d_in[11];
  const float* fmf_w1 = (const float*)d_in[12]; const float* fmf_b1 = (const float*)d_in[13];
  const float* fmf_w2 = (const float*)d_in[14]; const float* fmf_b2 = (const float*)d_in[15];
  const float* ow1    = (const float*)d_in[16]; const float* ob1    = (const float*)d_in[17];
  const float* ow2    = (const float*)d_in[18]; const float* ob2    = (const float*)d_in[19];

  int NL = in_sizes[0] / EMB;
  int NR = in_sizes[1] / EMB;
  int E  = in_sizes[2] / EMB;
  const int* srcv = eidx;
  const int* dstv = eidx + E;

  char* base = (char*)d_ws;
  size_t o = 0;
  u16* hbf = (u16*)(base + o);      o += (size_t)E * EMB * sizeof(u16);
  float* P_i  = (float*)(base + o); o += (size_t)NR * EMB * 4;
  float* P_j  = (float*)(base + o); o += (size_t)NL * EMB * 4;
  float* h_o  = (float*)(base + o); o += (size_t)NR * EMB * 4;
  float* Weff_i = (float*)(base + o); o += EMB * EMB * 4;
  float* beff_i = (float*)(base + o); o += EMB * 4;
  float* Weff_j = (float*)(base + o); o += EMB * EMB * 4;
  float* beff_j = (float*)(base + o); o += EMB * 4;
  float* Weff_e = (float*)(base + o); o += EMB * EMB * 4;
  float* beff_e = (float*)(base + o); o += EMB * 4;
  float* W2p  = (float*)(base + o); o += EMB * EMB * 4;
  float* b2p  = (float*)(base + o); o += EMB * 4;
  float* W2o  = (float*)(base + o); o += EMB * EMB * 4;
  float* b2o  = (float*)(base + o); o += EMB * 4;
  u16* fragA1 = (u16*)(base + o); o += 512 * 8 * sizeof(u16);
  u16* fragA2 = (u16*)(base + o); o += 512 * 8 * sizeof(u16);
  u16* fragW2 = (u16*)(base + o); o += 512 * 8 * sizeof(u16);
  // ---- zeroed region starts here ----
  char* zstart = base + o;
  float* agg     = (float*)(base + o); o += (size_t)NR * EMB * 4;
  int* cnt_dst   = (int*)(base + o);   o += (size_t)NR * 4;
  int* cnt_src   = (int*)(base + o);   o += (size_t)NL * 4;
  float* musum_i = (float*)(base + o); o += EMB * 4;
  float* S_i     = (float*)(base + o); o += EMB * EMB * 4;
  float* musum_j = (float*)(base + o); o += EMB * 4;
  float* S_j     = (float*)(base + o); o += EMB * EMB * 4;
  float* musum_e = (float*)(base + o); o += EMB * 4;
  float* S_e     = (float*)(base + o); o += EMB * EMB * 4;
  float* hsum    = (float*)(base + o); o += EMB * 4;
  float* hsq     = (float*)(base + o); o += EMB * 4;
  float* osum    = (float*)(base + o); o += EMB * 4;
  float* osq     = (float*)(base + o); o += EMB * 4;
  int zn = (int)(((base + o) - zstart) / 4);

  float invE = 1.0f / (float)E;
  float invNR = 1.0f / (float)NR;
  int ntE = E >> 4;   // 16-edge tiles (E % 16 == 0 for this workload)

  kzero<<<512, 256, 0, stream>>>((float*)zstart, zn);
  kcount<<<512, 256, 0, stream>>>(srcv, dstv, E, cnt_src, cnt_dst);
  kprepm<<<1024, 256, 0, stream>>>(edgef, E, musum_e, S_e);
  kgram<<<256, 256, 0, stream>>>(right, cnt_dst, NR, musum_i, S_i);
  kgram<<<256, 256, 0, stream>>>(left,  cnt_src, NL, musum_j, S_j);
  keffw<<<1, 256, 0, stream>>>(musum_i, S_i, fmr_w1, fmr_b1, fmr_w2, fmr_b2, invE, Weff_i, beff_i);
  keffw<<<1, 256, 0, stream>>>(musum_j, S_j, fmr_w1, fmr_b1, fmr_w2, fmr_b2, invE, Weff_j, beff_j);
  keffw<<<1, 256, 0, stream>>>(musum_e, S_e, fme_w1, fme_b1, fme_w2, fme_b2, invE, Weff_e, beff_e);
  kfrag<<<1, 256, 0, stream>>>(Weff_e, fragA1, 0);
  kfrag<<<1, 256, 0, stream>>>(fmf_w1 + EMB * EMB, fragA2, 1);
  knodeMP<<<1024, 256, 0, stream>>>(right, Weff_i, beff_i, fmf_w1,                 NR, P_i);
  knodeMP<<<1024, 256, 0, stream>>>(left,  Weff_j, beff_j, fmf_w1 + 2 * EMB * EMB, NL, P_j);
  kpass1m<<<1024, 256, 0, stream>>>(edgef, srcv, dstv, fragA1, fragA2, beff_e,
                                    fmf_b1, P_i, P_j, ntE, hbf, hsum, hsq);
  kbnfold<<<1, 256, 0, stream>>>(hsum, hsq, invE, fmf_w2, fmf_b2, W2p, b2p);
  kfrag<<<1, 256, 0, stream>>>(W2p, fragW2, 1);
  kpass2m<<<1024, 256, 0, stream>>>(hbf, dstv, fragW2, b2p, ntE, agg);
  kout1<<<1024, 256, 0, stream>>>(agg, cnt_dst, right, ow1, ob1, NR, h_o, osum, osq);
  kbnfold<<<1, 256, 0, stream>>>(osum, osq, invNR, ow2, ob2, W2o, b2o);
  kout2<<<1024, 256, 0, stream>>>(h_o, W2o, b2o, NR, (float*)d_out);
}

// Round 4
// 1334.044 us; speedup vs baseline: 1.8183x; 1.0940x over previous
//
#include <hip/hip_runtime.h>

#define EMB 64
#define BNEPS 1e-5f

typedef unsigned short u16;
typedef float f32x4 __attribute__((ext_vector_type(4)));
typedef short bf16x8 __attribute__((ext_vector_type(8)));
typedef short bf16x4 __attribute__((ext_vector_type(4)));

__device__ __forceinline__ float bf2f(u16 u){
  union { unsigned int i; float f; } v; v.i = ((unsigned int)u) << 16; return v.f;
}
__device__ __forceinline__ u16 f2bf(float x){
  union { float f; unsigned int i; } v; v.f = x;
  unsigned int r = v.i + 0x7FFFu + ((v.i >> 16) & 1u);   // RNE
  return (u16)(r >> 16);
}
__device__ __forceinline__ void atomAddF(float* p, float v){
  __hip_atomic_fetch_add(p, v, __ATOMIC_RELAXED, __HIP_MEMORY_SCOPE_AGENT);
}

// ---------------- zero scratch ----------------
__global__ void kzero(float* __restrict__ p, int n){
  int i = blockIdx.x * blockDim.x + threadIdx.x;
  int st = gridDim.x * blockDim.x;
  for (; i < n; i += st) p[i] = 0.f;
}

// ---------------- per-node edge-endpoint counts ----------------
__global__ void kcount(const int* __restrict__ src, const int* __restrict__ dst,
                       int E, int* __restrict__ cs, int* __restrict__ cd){
  int i = blockIdx.x * blockDim.x + threadIdx.x;
  int st = gridDim.x * blockDim.x;
  for (; i < E; i += st){
    atomicAdd(&cd[dst[i]], 1);
    atomicAdd(&cs[src[i]], 1);
  }
}

// ---------------- (weighted) column-mean + Gram of rows (node-scale, fp32) ----------------
__global__ __launch_bounds__(256) void kgram(const float* __restrict__ X,
    const int* __restrict__ cnt, int N,
    float* __restrict__ musum, float* __restrict__ S){
  __shared__ float xs[4][EMB];
  __shared__ float cs[4];
  int t = threadIdx.x, r = t >> 6, j = t & 63;
  int a = t >> 2, bb = (t & 3) << 4;
  float g[16];
  #pragma unroll
  for (int i = 0; i < 16; i++) g[i] = 0.f;
  float mup = 0.f;
  for (int n0 = blockIdx.x * 4; n0 < N; n0 += gridDim.x * 4){
    int n = n0 + r; bool ok = n < N;
    xs[r][j] = ok ? X[(size_t)n * EMB + j] : 0.f;
    if (j == 0) cs[r] = ok ? (cnt ? (float)cnt[n] : 1.f) : 0.f;
    __syncthreads();
    #pragma unroll
    for (int rr = 0; rr < 4; rr++){
      float xa = cs[rr] * xs[rr][a];
      const float4* x4 = (const float4*)&xs[rr][bb];
      #pragma unroll
      for (int i4 = 0; i4 < 4; i4++){
        float4 v = x4[i4];
        g[4*i4+0] += xa * v.x; g[4*i4+1] += xa * v.y;
        g[4*i4+2] += xa * v.z; g[4*i4+3] += xa * v.w;
      }
    }
    if (t < EMB) mup += cs[0]*xs[0][t] + cs[1]*xs[1][t] + cs[2]*xs[2][t] + cs[3]*xs[3][t];
    __syncthreads();
  }
  #pragma unroll
  for (int i = 0; i < 16; i++) atomAddF(&S[a * EMB + bb + i], g[i]);
  if (t < EMB) atomAddF(&musum[t], mup);
}

// ---------------- MFMA Gram + column means over edge features; also emits bf16 XE ----------------
__global__ __launch_bounds__(256) void kprepm(const float* __restrict__ XE, int N,
    float* __restrict__ musum, float* __restrict__ S, u16* __restrict__ XEb){
  __shared__ __align__(16) u16 XT[64 * 72];
  int t = threadIdx.x, l = t & 63, wv = t >> 6, g = l >> 4, e16 = l & 15;
  f32x4 C[4];
  #pragma unroll
  for (int mb = 0; mb < 4; mb++) C[mb] = (f32x4){0.f,0.f,0.f,0.f};
  float ms[4] = {0.f, 0.f, 0.f, 0.f};
  int ntiles = N >> 6;
  for (int T = blockIdx.x; T < ntiles; T += gridDim.x){
    __syncthreads();
    #pragma unroll
    for (int i = 0; i < 4; i++){
      int c = t + i * 256;
      int row = c >> 4, k0 = (c & 15) << 2;
      size_t grow = (size_t)T * 64 + row;
      f32x4 v = *(const f32x4*)(XE + grow * EMB + k0);
      u16 w4[4];
      #pragma unroll
      for (int q = 0; q < 4; q++){
        ms[q] += v[q];
        w4[q] = f2bf(v[q]);
        XT[(k0 + q) * 72 + row] = w4[q];
      }
      if (XEb) *(bf16x4*)(XEb + grow * EMB + k0) = *(bf16x4*)w4;
    }
    __syncthreads();
    #pragma unroll
    for (int kf = 0; kf < 2; kf++){
      bf16x8 fr[4];
      #pragma unroll
      for (int mb = 0; mb < 4; mb++)
        fr[mb] = *(const bf16x8*)&XT[(mb*16 + e16) * 72 + kf*32 + g*8];
      bf16x8 bfr = *(const bf16x8*)&XT[(wv*16 + e16) * 72 + kf*32 + g*8];
      #pragma unroll
      for (int mb = 0; mb < 4; mb++)
        C[mb] = __builtin_amdgcn_mfma_f32_16x16x32_bf16(fr[mb], bfr, C[mb], 0, 0, 0);
    }
  }
  #pragma unroll
  for (int mb = 0; mb < 4; mb++)
    #pragma unroll
    for (int r = 0; r < 4; r++)
      atomAddF(&S[(mb*16 + g*4 + r) * EMB + wv*16 + e16], C[mb][r]);
  __syncthreads();
  float* red = (float*)XT;
  #pragma unroll
  for (int q = 0; q < 4; q++){
    float x = ms[q];
    x += __shfl_xor(x, 16); x += __shfl_xor(x, 32);
    if (l < 16) red[(wv*16 + l)*4 + q] = x;
  }
  __syncthreads();
  if (t < 64){
    int k = t >> 2, q = t & 3;
    float s = red[(k)*4+q] + red[(16+k)*4+q] + red[(32+k)*4+q] + red[(48+k)*4+q];
    atomAddF(&musum[k*4 + q], s);
  }
}

// ---------------- fold BN(stats of h=x@w1+b1) + w2 into (Weff, beff) ----------------
__global__ __launch_bounds__(256) void keffw(const float* __restrict__ musum,
    const float* __restrict__ S, const float* __restrict__ w1, const float* __restrict__ b1,
    const float* __restrict__ w2, const float* __restrict__ b2, float invN,
    float* __restrict__ Weff, float* __restrict__ beff){
  __shared__ float mu[EMB];
  __shared__ float C[EMB][EMB];
  __shared__ float W1p[EMB][EMB + 1];
  __shared__ float c1[EMB];
  __shared__ float istd[EMB];
  __shared__ float red[256];
  int t = threadIdx.x;
  if (t < EMB) mu[t] = musum[t] * invN;
  __syncthreads();
  for (int e = t; e < EMB * EMB; e += 256){
    int k = e >> 6, l = e & 63;
    C[k][l] = S[e] * invN - mu[k] * mu[l];
  }
  __syncthreads();
  {
    int j = t & 63, kg = t >> 6;
    float part = 0.f;
    for (int k = kg * 16; k < kg * 16 + 16; k++){
      float inner = 0.f;
      for (int l = 0; l < EMB; l++) inner += C[k][l] * w1[l * EMB + j];
      part += w1[k * EMB + j] * inner;
    }
    red[t] = part;
  }
  __syncthreads();
  if (t < EMB){
    float var = red[t] + red[t + 64] + red[t + 128] + red[t + 192];
    float is = 1.0f / sqrtf(var + BNEPS);
    istd[t] = is;
    float muh = 0.f;
    for (int k = 0; k < EMB; k++) muh += mu[k] * w1[k * EMB + t];
    muh += b1[t];
    c1[t] = (b1[t] - muh) * is;
  }
  __syncthreads();
  for (int e = t; e < EMB * EMB; e += 256){
    int k = e >> 6, j = e & 63;
    W1p[k][j] = w1[e] * istd[j];
  }
  __syncthreads();
  {
    int k = t >> 2, j2b = (t & 3) << 4;
    float acc[16];
    #pragma unroll
    for (int i = 0; i < 16; i++) acc[i] = 0.f;
    for (int j = 0; j < EMB; j++){
      float wp = W1p[k][j];
      const float* w2r = &w2[j * EMB + j2b];
      #pragma unroll
      for (int i = 0; i < 16; i++) acc[i] += wp * w2r[i];
    }
    #pragma unroll
    for (int i = 0; i < 16; i++) Weff[k * EMB + j2b + i] = acc[i];
  }
  if (t < EMB){
    float acc = b2[t];
    for (int j = 0; j < EMB; j++) acc += c1[j] * w2[j * EMB + t];
    beff[t] = acc;
  }
}

// ---------------- weight -> frag-major bf16 ----------------
__global__ void kfrag(const float* __restrict__ W, u16* __restrict__ F, int pi){
  int t = threadIdx.x;
  for (int ent = t; ent < 512; ent += 256){
    int mb = ent >> 7, kf = (ent >> 6) & 1, l = ent & 63;
    int g = (l >> 4), e16 = l & 15;
    u16 out[8];
    #pragma unroll
    for (int i = 0; i < 8; i++){
      int row = pi ? ((kf + 2*(i>>2))*16 + g*4 + (i&3)) : (kf*32 + g*8 + i);
      out[i] = f2bf(W[row * EMB + mb*16 + e16]);
    }
    *(bf16x8*)(F + ent * 8) = *(bf16x8*)out;
  }
}

// ---------------- per-node: P = relu(x@Weff+beff) @ Wslice  (bf16 output) ----------------
__global__ __launch_bounds__(256) void knodeMP(const float* __restrict__ X,
    const float* __restrict__ Weff, const float* __restrict__ beff,
    const float* __restrict__ Wslice, int N, u16* __restrict__ P){
  __shared__ float xs[4][EMB];
  __shared__ float ms[4][EMB];
  __shared__ float be[EMB];
  int t = threadIdx.x, r = t >> 6, j = t & 63;
  float wA[EMB], wB[EMB];
  #pragma unroll
  for (int k = 0; k < EMB; k++){ wA[k] = Weff[k * EMB + j]; wB[k] = Wslice[k * EMB + j]; }
  if (t < EMB) be[t] = beff[t];
  __syncthreads();
  for (int n0 = blockIdx.x * 4; n0 < N; n0 += gridDim.x * 4){
    int n = n0 + r; bool ok = n < N;
    xs[r][j] = ok ? X[(size_t)n * EMB + j] : 0.f;
    __syncthreads();
    float a0 = be[j], a1 = 0.f, a2 = 0.f, a3 = 0.f;
    const float4* x4 = (const float4*)xs[r];
    #pragma unroll
    for (int kb = 0; kb < 16; kb++){
      float4 v = x4[kb];
      a0 += v.x * wA[4*kb]; a1 += v.y * wA[4*kb+1];
      a2 += v.z * wA[4*kb+2]; a3 += v.w * wA[4*kb+3];
    }
    ms[r][j] = fmaxf((a0 + a1) + (a2 + a3), 0.f);
    __syncthreads();
    float p0 = 0.f, p1 = 0.f, p2 = 0.f, p3 = 0.f;
    const float4* m4 = (const float4*)ms[r];
    #pragma unroll
    for (int kb = 0; kb < 16; kb++){
      float4 v = m4[kb];
      p0 += v.x * wB[4*kb]; p1 += v.y * wB[4*kb+1];
      p2 += v.z * wB[4*kb+2]; p3 += v.w * wB[4*kb+3];
    }
    if (ok) P[(size_t)n * EMB + j] = f2bf((p0 + p1) + (p2 + p3));
    __syncthreads();
  }
}

// ---------------- MFMA pass 1 (bf16 gathers, no stats) ----------------
__global__ __launch_bounds__(256) void kpass1m(const float* __restrict__ XE,
    const u16* __restrict__ XEb,
    const int* __restrict__ srcv, const int* __restrict__ dstv,
    const u16* __restrict__ fragA1, const u16* __restrict__ fragA2,
    const float* __restrict__ beff_e, const float* __restrict__ bf1,
    const u16* __restrict__ Pib, const u16* __restrict__ Pjb, int ntiles,
    u16* __restrict__ hbf){
  int t = threadIdx.x, l = t & 63, wv = t >> 6, g = l >> 4, e16 = l & 15;
  bf16x8 a1w[4][2], a2w[4][2];
  #pragma unroll
  for (int mb = 0; mb < 4; mb++)
    #pragma unroll
    for (int kf = 0; kf < 2; kf++){
      a1w[mb][kf] = *(const bf16x8*)(fragA1 + ((size_t)((mb*2+kf)*64 + l)) * 8);
      a2w[mb][kf] = *(const bf16x8*)(fragA2 + ((size_t)((mb*2+kf)*64 + l)) * 8);
    }
  f32x4 b1v[4], b2v[4];
  #pragma unroll
  for (int mb = 0; mb < 4; mb++)
    #pragma unroll
    for (int r = 0; r < 4; r++){
      b1v[mb][r] = beff_e[mb*16 + g*4 + r];
      b2v[mb][r] = bf1[mb*16 + g*4 + r];
    }

  int gw = blockIdx.x * 4 + wv, nw = gridDim.x * 4;
  int d_n = 0, s_n = 0;
  if (gw < ntiles){ d_n = dstv[gw*16 + e16]; s_n = srcv[gw*16 + e16]; }
  for (int T = gw; T < ntiles; T += nw){
    int d = d_n, s = s_n;
    // edge features as ready-made bf16 frags (fallback: f32 + convert)
    bf16x8 xf0, xf1;
    if (XEb){
      const u16* xr = XEb + (size_t)(T*16 + e16) * EMB;
      xf0 = *(const bf16x8*)(xr + g*8);
      xf1 = *(const bf16x8*)(xr + 32 + g*8);
    } else {
      const float* xr = XE + (size_t)(T*16 + e16) * EMB;
      f32x4 x0 = *(const f32x4*)(xr + g*8);
      f32x4 x1 = *(const f32x4*)(xr + g*8 + 4);
      f32x4 x2 = *(const f32x4*)(xr + 32 + g*8);
      f32x4 x3 = *(const f32x4*)(xr + 36 + g*8);
      #pragma unroll
      for (int q = 0; q < 4; q++){
        xf0[q]   = (short)f2bf(x0[q]); xf0[4+q] = (short)f2bf(x1[q]);
        xf1[q]   = (short)f2bf(x2[q]); xf1[4+q] = (short)f2bf(x3[q]);
      }
    }
    // bf16 P gathers: lane (g,e16) takes P[row][mb*16+g*4 .. +3]
    const u16* pib = Pib + (size_t)d * EMB;
    const u16* pjb = Pjb + (size_t)s * EMB;
    bf16x4 piv[4], pjv[4];
    #pragma unroll
    for (int mb = 0; mb < 4; mb++){
      piv[mb] = *(const bf16x4*)(pib + mb*16 + g*4);
      pjv[mb] = *(const bf16x4*)(pjb + mb*16 + g*4);
    }
    // prefetch next tile's indices
    int T2 = T + nw;
    if (T2 < ntiles){ d_n = dstv[T2*16 + e16]; s_n = srcv[T2*16 + e16]; }
    // init layer2 accum with bias + P gathers
    f32x4 C2[4];
    #pragma unroll
    for (int mb = 0; mb < 4; mb++)
      #pragma unroll
      for (int r = 0; r < 4; r++)
        C2[mb][r] = b2v[mb][r] + bf2f((u16)piv[mb][r]) + bf2f((u16)pjv[mb][r]);
    // layer 1 (transposed)
    f32x4 C1[4];
    #pragma unroll
    for (int mb = 0; mb < 4; mb++) C1[mb] = b1v[mb];
    #pragma unroll
    for (int mb = 0; mb < 4; mb++){
      C1[mb] = __builtin_amdgcn_mfma_f32_16x16x32_bf16(a1w[mb][0], xf0, C1[mb], 0, 0, 0);
      C1[mb] = __builtin_amdgcn_mfma_f32_16x16x32_bf16(a1w[mb][1], xf1, C1[mb], 0, 0, 0);
    }
    // relu + pack into layer2 A-frags via pi
    bf16x8 mfr0, mfr1;
    #pragma unroll
    for (int q = 0; q < 4; q++){
      mfr0[q]   = (short)f2bf(fmaxf(C1[0][q], 0.f));
      mfr0[4+q] = (short)f2bf(fmaxf(C1[2][q], 0.f));
      mfr1[q]   = (short)f2bf(fmaxf(C1[1][q], 0.f));
      mfr1[4+q] = (short)f2bf(fmaxf(C1[3][q], 0.f));
    }
    // layer 2 (transposed)
    #pragma unroll
    for (int mb = 0; mb < 4; mb++){
      C2[mb] = __builtin_amdgcn_mfma_f32_16x16x32_bf16(a2w[mb][0], mfr0, C2[mb], 0, 0, 0);
      C2[mb] = __builtin_amdgcn_mfma_f32_16x16x32_bf16(a2w[mb][1], mfr1, C2[mb], 0, 0, 0);
    }
    bf16x8 h0, h1;
    #pragma unroll
    for (int q = 0; q < 4; q++){
      h0[q]   = (short)f2bf(C2[0][q]); h0[4+q] = (short)f2bf(C2[2][q]);
      h1[q]   = (short)f2bf(C2[1][q]); h1[4+q] = (short)f2bf(C2[3][q]);
    }
    *(bf16x8*)(hbf + ((size_t)(T*2 + 0) * 64 + l) * 8) = h0;
    *(bf16x8*)(hbf + ((size_t)(T*2 + 1) * 64 + l) * 8) = h1;
  }
}

// ---------------- streaming stats over hbf (sum, sumsq per column) ----------------
// word W holds h[edge][col] with col = (u + 2*(i>>2))*16 + g*4 + (i&3),
// u = (W>>6)&1, g = (W&63)>>4. Grid-stride keeps u wave-uniform.
__global__ __launch_bounds__(256) void kstat(const u16* __restrict__ hbf, long nwords,
    float* __restrict__ hsum, float* __restrict__ hsq){
  int t = threadIdx.x, l = t & 63, wv = t >> 6, g = l >> 4, e16 = l & 15;
  long gid = (long)blockIdx.x * 256 + t;
  long stride = (long)gridDim.x * 256;   // stride/64 is even -> u fixed per thread
  int u = wv & 1;
  float s[8], q[8];
  #pragma unroll
  for (int i = 0; i < 8; i++){ s[i] = 0.f; q[i] = 0.f; }
  for (long W = gid; W < nwords; W += stride){
    bf16x8 h = *(const bf16x8*)(hbf + W * 8);
    #pragma unroll
    for (int i = 0; i < 8; i++){
      float v = bf2f((u16)h[i]);
      s[i] += v; q[i] += v * v;
    }
  }
  #pragma unroll
  for (int i = 0; i < 8; i++){
    float v = s[i], w = q[i];
    #pragma unroll
    for (int m = 1; m < 16; m <<= 1){ v += __shfl_xor(v, m); w += __shfl_xor(w, m); }
    if (e16 == 0){
      int c = (u + 2*(i>>2))*16 + g*4 + (i&3);
      atomAddF(&hsum[c], v);
      atomAddF(&hsq[c], w);
    }
  }
}

// ---------------- fold BN stats + w2 into (W2p, b2p) ----------------
__global__ __launch_bounds__(256) void kbnfold(const float* __restrict__ hsum,
    const float* __restrict__ hsq, float invN, const float* __restrict__ w2,
    const float* __restrict__ b2, float* __restrict__ W2p, float* __restrict__ b2p){
  __shared__ float mu[EMB], istd[EMB];
  int t = threadIdx.x;
  if (t < EMB){
    float m = hsum[t] * invN;
    float var = hsq[t] * invN - m * m;
    mu[t] = m; istd[t] = 1.0f / sqrtf(var + BNEPS);
  }
  __syncthreads();
  for (int e = t; e < EMB * EMB; e += 256){
    int k = e >> 6;
    W2p[e] = istd[k] * w2[e];
  }
  if (t < EMB){
    float acc = b2[t];
    for (int k = 0; k < EMB; k++) acc -= mu[k] * istd[k] * w2[k * EMB + t];
    b2p[t] = acc;
  }
}

// ---------------- MFMA pass 2: msg = relu(h@W2p+b2p); agg[dst] += msg ----------------
__global__ __launch_bounds__(256) void kpass2m(const u16* __restrict__ hbf,
    const int* __restrict__ dstv, const u16* __restrict__ fragW2,
    const float* __restrict__ b2p, int ntiles, float* __restrict__ agg){
  int t = threadIdx.x, l = t & 63, wv = t >> 6, g = l >> 4, e16 = l & 15;
  bf16x8 w2f[4][2];
  #pragma unroll
  for (int nb = 0; nb < 4; nb++)
    #pragma unroll
    for (int kf = 0; kf < 2; kf++)
      w2f[nb][kf] = *(const bf16x8*)(fragW2 + ((size_t)((nb*2+kf)*64 + l)) * 8);
  float bv[4];
  #pragma unroll
  for (int nb = 0; nb < 4; nb++) bv[nb] = b2p[nb*16 + e16];

  int gw = blockIdx.x * 4 + wv, nw = gridDim.x * 4;
  for (int T = gw; T < ntiles; T += nw){
    bf16x8 h0 = *(const bf16x8*)(hbf + ((size_t)(T*2 + 0) * 64 + l) * 8);
    bf16x8 h1 = *(const bf16x8*)(hbf + ((size_t)(T*2 + 1) * 64 + l) * 8);
    int4 dd = *(const int4*)(dstv + T*16 + g*4);
    int dr[4] = {dd.x, dd.y, dd.z, dd.w};
    f32x4 C[4];
    #pragma unroll
    for (int nb = 0; nb < 4; nb++) C[nb] = (f32x4){bv[nb], bv[nb], bv[nb], bv[nb]};
    #pragma unroll
    for (int nb = 0; nb < 4; nb++){
      C[nb] = __builtin_amdgcn_mfma_f32_16x16x32_bf16(h0, w2f[nb][0], C[nb], 0, 0, 0);
      C[nb] = __builtin_amdgcn_mfma_f32_16x16x32_bf16(h1, w2f[nb][1], C[nb], 0, 0, 0);
    }
    #pragma unroll
    for (int r = 0; r < 4; r++){
      float* ap = agg + (size_t)dr[r] * EMB + e16;
      #pragma unroll
      for (int nb = 0; nb < 4; nb++)
        atomAddF(ap + nb*16, fmaxf(C[nb][r], 0.f));
    }
  }
}

// ---------------- output stage 1 ----------------
__global__ __launch_bounds__(256) void kout1(const float* __restrict__ agg,
    const int* __restrict__ cnt, const float* __restrict__ right,
    const float* __restrict__ ow1, const float* __restrict__ ob1, int N,
    float* __restrict__ h_o, float* __restrict__ osum, float* __restrict__ osq){
  __shared__ float xs[4][2 * EMB];
  __shared__ float bsh[EMB];
  __shared__ float red[256];
  int t = threadIdx.x, r = t >> 6, j = t & 63;
  float wc[2 * EMB];
  #pragma unroll
  for (int k = 0; k < 2 * EMB; k++) wc[k] = ow1[k * EMB + j];
  if (t < EMB) bsh[t] = ob1[t];
  __syncthreads();
  float psum = 0.f, psq = 0.f;
  for (int n0 = blockIdx.x * 4; n0 < N; n0 += gridDim.x * 4){
    int n = n0 + r; bool ok = n < N;
    if (ok){
      float c = fmaxf((float)cnt[n], 1.f);
      xs[r][j] = agg[(size_t)n * EMB + j] / c;
      xs[r][EMB + j] = right[(size_t)n * EMB + j];
    } else { xs[r][j] = 0.f; xs[r][EMB + j] = 0.f; }
    __syncthreads();
    float a0 = bsh[j], a1 = 0.f, a2 = 0.f, a3 = 0.f;
    const float4* x4 = (const float4*)xs[r];
    #pragma unroll
    for (int kb = 0; kb < 32; kb++){
      float4 v = x4[kb];
      a0 += v.x * wc[4*kb]; a1 += v.y * wc[4*kb+1];
      a2 += v.z * wc[4*kb+2]; a3 += v.w * wc[4*kb+3];
    }
    if (ok){
      float h = (a0 + a1) + (a2 + a3);
      h_o[(size_t)n * EMB + j] = h;
      psum += h; psq += h * h;
    }
    __syncthreads();
  }
  red[t] = psum; __syncthreads();
  if (t < EMB) atomAddF(&osum[t], red[t] + red[t + 64] + red[t + 128] + red[t + 192]);
  __syncthreads();
  red[t] = psq; __syncthreads();
  if (t < EMB) atomAddF(&osq[t], red[t] + red[t + 64] + red[t + 128] + red[t + 192]);
}

// ---------------- output stage 2 ----------------
__global__ __launch_bounds__(256) void kout2(const float* __restrict__ h_o,
    const float* __restrict__ W2o, const float* __restrict__ b2o, int N,
    float* __restrict__ out){
  __shared__ float hs[4][EMB];
  __shared__ float bsh[EMB];
  int t = threadIdx.x, r = t >> 6, j = t & 63;
  float wc[EMB];
  #pragma unroll
  for (int k = 0; k < EMB; k++) wc[k] = W2o[k * EMB + j];
  if (t < EMB) bsh[t] = b2o[t];
  __syncthreads();
  for (int n0 = blockIdx.x * 4; n0 < N; n0 += gridDim.x * 4){
    int n = n0 + r; bool ok = n < N;
    hs[r][j] = ok ? h_o[(size_t)n * EMB + j] : 0.f;
    __syncthreads();
    float a0 = bsh[j], a1 = 0.f, a2 = 0.f, a3 = 0.f;
    const float4* h4 = (const float4*)hs[r];
    #pragma unroll
    for (int kb = 0; kb < 16; kb++){
      float4 v = h4[kb];
      a0 += v.x * wc[4*kb]; a1 += v.y * wc[4*kb+1];
      a2 += v.z * wc[4*kb+2]; a3 += v.w * wc[4*kb+3];
    }
    if (ok) out[(size_t)n * EMB + j] = fmaxf((a0 + a1) + (a2 + a3), 0.f);
    __syncthreads();
  }
}

extern "C" void kernel_launch(void* const* d_in, const int* in_sizes, int n_in,
                              void* d_out, int out_size, void* d_ws, size_t ws_size,
                              hipStream_t stream){
  const float* left   = (const float*)d_in[0];
  const float* right  = (const float*)d_in[1];
  const float* edgef  = (const float*)d_in[2];
  const int*   eidx   = (const int*)d_in[3];
  const float* fmr_w1 = (const float*)d_in[4];  const float* fmr_b1 = (const float*)d_in[5];
  const float* fmr_w2 = (const float*)d_in[6];  const float* fmr_b2 = (const float*)d_in[7];
  const float* fme_w1 = (const float*)d_in[8];  const float* fme_b1 = (const float*)d_in[9];
  const float* fme_w2 = (const float*)d_in[10]; const float* fme_b2 = (const float*)d_in[11];
  const float* fmf_w1 = (const float*)d_in[12]; const float* fmf_b1 = (const float*)d_in[13];
  const float* fmf_w2 = (const float*)d_in[14]; const float* fmf_b2 = (const float*)d_in[15];
  const float* ow1    = (const float*)d_in[16]; const float* ob1    = (const float*)d_in[17];
  const float* ow2    = (const float*)d_in[18]; const float* ob2    = (const float*)d_in[19];

  int NL = in_sizes[0] / EMB;
  int NR = in_sizes[1] / EMB;
  int E  = in_sizes[2] / EMB;
  const int* srcv = eidx;
  const int* dstv = eidx + E;

  char* base = (char*)d_ws;
  size_t o = 0;
  u16* hbf = (u16*)(base + o);      o += (size_t)E * EMB * sizeof(u16);
  u16* P_i  = (u16*)(base + o); o += (size_t)NR * EMB * sizeof(u16);
  u16* P_j  = (u16*)(base + o); o += (size_t)NL * EMB * sizeof(u16);
  float* h_o  = (float*)(base + o); o += (size_t)NR * EMB * 4;
  float* Weff_i = (float*)(base + o); o += EMB * EMB * 4;
  float* beff_i = (float*)(base + o); o += EMB * 4;
  float* Weff_j = (float*)(base + o); o += EMB * EMB * 4;
  float* beff_j = (float*)(base + o); o += EMB * 4;
  float* Weff_e = (float*)(base + o); o += EMB * EMB * 4;
  float* beff_e = (float*)(base + o); o += EMB * 4;
  float* W2p  = (float*)(base + o); o += EMB * EMB * 4;
  float* b2p  = (float*)(base + o); o += EMB * 4;
  float* W2o  = (float*)(base + o); o += EMB * EMB * 4;
  float* b2o  = (float*)(base + o); o += EMB * 4;
  u16* fragA1 = (u16*)(base + o); o += 512 * 8 * sizeof(u16);
  u16* fragA2 = (u16*)(base + o); o += 512 * 8 * sizeof(u16);
  u16* fragW2 = (u16*)(base + o); o += 512 * 8 * sizeof(u16);
  // ---- zeroed region starts here ----
  char* zstart = base + o;
  float* agg     = (float*)(base + o); o += (size_t)NR * EMB * 4;
  int* cnt_dst   = (int*)(base + o);   o += (size_t)NR * 4;
  int* cnt_src   = (int*)(base + o);   o += (size_t)NL * 4;
  float* musum_i = (float*)(base + o); o += EMB * 4;
  float* S_i     = (float*)(base + o); o += EMB * EMB * 4;
  float* musum_j = (float*)(base + o); o += EMB * 4;
  float* S_j     = (float*)(base + o); o += EMB * EMB * 4;
  float* musum_e = (float*)(base + o); o += EMB * 4;
  float* S_e     = (float*)(base + o); o += EMB * EMB * 4;
  float* hsum    = (float*)(base + o); o += EMB * 4;
  float* hsq     = (float*)(base + o); o += EMB * 4;
  float* osum    = (float*)(base + o); o += EMB * 4;
  float* osq     = (float*)(base + o); o += EMB * 4;
  int zn = (int)(((base + o) - zstart) / 4);
  // optional bf16 edge-feature copy (fragment-friendly layout), placed last
  u16* XEb = nullptr;
  size_t xeb_bytes = (size_t)E * EMB * sizeof(u16);
  if (o + xeb_bytes <= ws_size){ XEb = (u16*)(base + o); o += xeb_bytes; }

  float invE = 1.0f / (float)E;
  float invNR = 1.0f / (float)NR;
  int ntE = E >> 4;   // 16-edge tiles (E % 16 == 0 for this workload)

  kzero<<<512, 256, 0, stream>>>((float*)zstart, zn);
  kcount<<<512, 256, 0, stream>>>(srcv, dstv, E, cnt_src, cnt_dst);
  kprepm<<<1024, 256, 0, stream>>>(edgef, E, musum_e, S_e, XEb);
  kgram<<<256, 256, 0, stream>>>(right, cnt_dst, NR, musum_i, S_i);
  kgram<<<256, 256, 0, stream>>>(left,  cnt_src, NL, musum_j, S_j);
  keffw<<<1, 256, 0, stream>>>(musum_i, S_i, fmr_w1, fmr_b1, fmr_w2, fmr_b2, invE, Weff_i, beff_i);
  keffw<<<1, 256, 0, stream>>>(musum_j, S_j, fmr_w1, fmr_b1, fmr_w2, fmr_b2, invE, Weff_j, beff_j);
  keffw<<<1, 256, 0, stream>>>(musum_e, S_e, fme_w1, fme_b1, fme_w2, fme_b2, invE, Weff_e, beff_e);
  kfrag<<<1, 256, 0, stream>>>(Weff_e, fragA1, 0);
  kfrag<<<1, 256, 0, stream>>>(fmf_w1 + EMB * EMB, fragA2, 1);
  knodeMP<<<1024, 256, 0, stream>>>(right, Weff_i, beff_i, fmf_w1,                 NR, P_i);
  knodeMP<<<1024, 256, 0, stream>>>(left,  Weff_j, beff_j, fmf_w1 + 2 * EMB * EMB, NL, P_j);
  kpass1m<<<1536, 256, 0, stream>>>(edgef, XEb, srcv, dstv, fragA1, fragA2, beff_e,
                                    fmf_b1, P_i, P_j, ntE, hbf);
  kstat<<<1024, 256, 0, stream>>>(hbf, (long)E * 8, hsum, hsq);
  kbnfold<<<1, 256, 0, stream>>>(hsum, hsq, invE, fmf_w2, fmf_b2, W2p, b2p);
  kfrag<<<1, 256, 0, stream>>>(W2p, fragW2, 1);
  kpass2m<<<1024, 256, 0, stream>>>(hbf, dstv, fragW2, b2p, ntE, agg);
  kout1<<<1024, 256, 0, stream>>>(agg, cnt_dst, right, ow1, ob1, NR, h_o, osum, osq);
  kbnfold<<<1, 256, 0, stream>>>(osum, osq, invNR, ow2, ob2, W2o, b2o);
  kout2<<<1024, 256, 0, stream>>>(h_o, W2o, b2o, NR, (float*)d_out);
}